// Round 4
// baseline (2180.731 us; speedup 1.0000x reference)
//
#include <hip/hip_runtime.h>
#include <hip/hip_bf16.h>
#include <hip/hip_fp16.h>

typedef _Float16 f16;
typedef _Float16 f16x8 __attribute__((ext_vector_type(8)));
typedef float f32x4 __attribute__((ext_vector_type(4)));

constexpr int EE     = 512;
constexpr int NMEM   = 50000;
constexpr int BQ     = 8192;
constexpr int NSEG   = 8;
constexpr int SEGLEN = NMEM / NSEG;       // 6250
constexpr int NT     = (SEGLEN + 15) / 16; // 391
constexpr int NC     = 8;                  // candidates kept per segment

// ---------------- prep: f32 -> fp16 keys + f64/f32 row norms ----------------
__global__ __launch_bounds__(256) void k_prep_keys(const float* __restrict__ mk,
                                                   f16* __restrict__ kh,
                                                   float* __restrict__ sq32,
                                                   double* __restrict__ sq64) {
  int row  = blockIdx.x * 4 + (threadIdx.x >> 6);
  int lane = threadIdx.x & 63;
  const float4* src = (const float4*)(mk + (size_t)row * EE) + lane * 2;
  float4 a = src[0], b = src[1];
  double s = (double)a.x*a.x + (double)a.y*a.y + (double)a.z*a.z + (double)a.w*a.w
           + (double)b.x*b.x + (double)b.y*b.y + (double)b.z*b.z + (double)b.w*b.w;
  f16x8 h;
  h[0]=(f16)a.x; h[1]=(f16)a.y; h[2]=(f16)a.z; h[3]=(f16)a.w;
  h[4]=(f16)b.x; h[5]=(f16)b.y; h[6]=(f16)b.z; h[7]=(f16)b.w;
  *((f16x8*)(kh + (size_t)row * EE) + lane) = h;
  #pragma unroll
  for (int o = 32; o > 0; o >>= 1) s += __shfl_down(s, o);
  if (lane == 0) { sq64[row] = s; sq32[row] = (float)s; }
}

__global__ __launch_bounds__(256) void k_prep_q(const float* __restrict__ Q,
                                                f16* __restrict__ qh) {
  int row  = blockIdx.x * 4 + (threadIdx.x >> 6);
  int lane = threadIdx.x & 63;
  const float4* src = (const float4*)(Q + (size_t)row * EE) + lane * 2;
  float4 a = src[0], b = src[1];
  f16x8 h;
  h[0]=(f16)a.x; h[1]=(f16)a.y; h[2]=(f16)a.z; h[3]=(f16)a.w;
  h[4]=(f16)b.x; h[5]=(f16)b.y; h[6]=(f16)b.z; h[7]=(f16)b.w;
  *((f16x8*)(qh + (size_t)row * EE) + lane) = h;
}

// ---------------- compose weights: Wc_m = Win_m @ W_m (f32) ----------------
__global__ __launch_bounds__(256) void k_compose(const float* __restrict__ Wq, const float* __restrict__ Wk,
                                                 const float* __restrict__ Wv, const float* __restrict__ Wiq,
                                                 const float* __restrict__ Wik, const float* __restrict__ Wiv,
                                                 float* __restrict__ Wc) {
  int m = blockIdx.z;
  const float* A = (m == 0) ? Wiq : ((m == 1) ? Wik : Wiv);
  const float* B = (m == 0) ? Wq  : ((m == 1) ? Wk  : Wv);
  float* C = Wc + (size_t)m * EE * EE;
  __shared__ float As[64][33];
  __shared__ float Bs[32][65];
  int i0 = blockIdx.x * 64, j0 = blockIdx.y * 64;
  int tx = threadIdx.x & 15, ty = threadIdx.x >> 4;
  float acc[4][4] = {};
  for (int kb = 0; kb < EE; kb += 32) {
    __syncthreads();
    #pragma unroll
    for (int v = 0; v < 8; ++v) {
      int idx = threadIdx.x + v * 256;
      As[idx >> 5][idx & 31] = A[(size_t)(i0 + (idx >> 5)) * EE + kb + (idx & 31)];
    }
    #pragma unroll
    for (int v = 0; v < 8; ++v) {
      int idx = threadIdx.x + v * 256;
      Bs[idx >> 6][idx & 63] = B[(size_t)(kb + (idx >> 6)) * EE + j0 + (idx & 63)];
    }
    __syncthreads();
    for (int t = 0; t < 32; ++t) {
      float av[4], bv[4];
      #pragma unroll
      for (int u = 0; u < 4; ++u) av[u] = As[ty*4+u][t];
      #pragma unroll
      for (int u = 0; u < 4; ++u) bv[u] = Bs[t][tx*4+u];
      #pragma unroll
      for (int a = 0; a < 4; ++a)
        #pragma unroll
        for (int b = 0; b < 4; ++b) acc[a][b] = fmaf(av[a], bv[b], acc[a][b]);
    }
  }
  #pragma unroll
  for (int a = 0; a < 4; ++a)
    #pragma unroll
    for (int b = 0; b < 4; ++b)
      C[(size_t)(i0 + ty*4 + a) * EE + j0 + tx*4 + b] = acc[a][b];
}

__global__ void k_bias(const float* __restrict__ Wiq, const float* __restrict__ Wik,
                       const float* __restrict__ Wiv, const float* __restrict__ bqv,
                       const float* __restrict__ bkv, const float* __restrict__ bvv,
                       const float* __restrict__ b_in, float* __restrict__ bc) {
  int m = blockIdx.x;
  const float* Wi = (m == 0) ? Wiq : ((m == 1) ? Wik : Wiv);
  const float* bb = (m == 0) ? bqv : ((m == 1) ? bkv : bvv);
  for (int i = threadIdx.x; i < EE; i += blockDim.x) {
    float s = 0.f;
    for (int t = 0; t < EE; ++t) s = fmaf(Wi[(size_t)i * EE + t], bb[t], s);
    bc[m * EE + i] = s + b_in[m * EE + i];
  }
}

// ---------------- stage 1: fp16 MFMA scores + per-segment top-8 ----------------
__global__ __launch_bounds__(512, 2) void k_stage1(const f16* __restrict__ Qh,
                                                   const f16* __restrict__ Kh,
                                                   const float* __restrict__ sq32,
                                                   int* __restrict__ part) {
  const int rb  = blockIdx.x;
  const int seg = blockIdx.y;
  const int tid = threadIdx.x;
  const int w   = tid >> 6;
  const int l   = tid & 63;
  const int lc  = l & 15, lp = l >> 4;
  const int seg_start = seg * SEGLEN;

  __shared__ f16   Bt[16 * 520];
  __shared__ float sqs[16];
  __shared__ float scratch[8][32][17];

  const int rowbase = rb * 256 + w * 32;
  f16x8 areg[2][16];
  #pragma unroll
  for (int m = 0; m < 2; ++m)
    #pragma unroll
    for (int ks = 0; ks < 16; ++ks)
      areg[m][ks] = *(const f16x8*)(Qh + (size_t)(rowbase + m*16 + lc) * EE + ks*32 + lp*8);

  float ts[NC]; int ti[NC];
  #pragma unroll
  for (int i = 0; i < NC; ++i) { ts[i] = -3.0e38f; ti[i] = 0; }

  float4 st0, st1; float stsq = 0.f;
  #define LOADT(tt) do { \
      int kk = seg_start + (tt) * 16; \
      int key0 = kk + (tid >> 6); \
      int key1 = key0 + 8; \
      key0 = key0 < NMEM ? key0 : NMEM - 1; \
      key1 = key1 < NMEM ? key1 : NMEM - 1; \
      st0 = *(const float4*)(Kh + (size_t)key0 * EE + (tid & 63) * 8); \
      st1 = *(const float4*)(Kh + (size_t)key1 * EE + (tid & 63) * 8); \
      if (tid < 16) { int kq = kk + tid; stsq = sq32[kq < NMEM ? kq : NMEM - 1]; } \
    } while (0)

  LOADT(0);
  for (int t = 0; t < NT; ++t) {
    __syncthreads();
    *(float4*)&Bt[(tid >> 6) * 520 + (tid & 63) * 8]       = st0;
    *(float4*)&Bt[((tid >> 6) + 8) * 520 + (tid & 63) * 8] = st1;
    if (tid < 16) sqs[tid] = stsq;
    __syncthreads();
    if (t + 1 < NT) LOADT(t + 1);

    f32x4 acc0 = {0,0,0,0}, acc1 = {0,0,0,0};
    #pragma unroll
    for (int ks = 0; ks < 16; ++ks) {
      f16x8 b = *(const f16x8*)&Bt[lc * 520 + ks * 32 + lp * 8];
      acc0 = __builtin_amdgcn_mfma_f32_16x16x32_f16(areg[0][ks], b, acc0, 0, 0, 0);
      acc1 = __builtin_amdgcn_mfma_f32_16x16x32_f16(areg[1][ks], b, acc1, 0, 0, 0);
    }
    float myq = sqs[lc];
    #pragma unroll
    for (int r = 0; r < 4; ++r) {
      scratch[w][lp*4 + r][lc]      = 2.0f * acc0[r] - myq;
      scratch[w][16 + lp*4 + r][lc] = 2.0f * acc1[r] - myq;
    }
    int nvalid = SEGLEN - t * 16; if (nvalid > 16) nvalid = 16;
    if (l < 32) {
      for (int c = 0; c < nvalid; ++c) {
        float s = scratch[w][l][c];
        if (s > ts[NC-1]) {
          ts[NC-1] = s; ti[NC-1] = seg_start + t * 16 + c;
          #pragma unroll
          for (int i = NC - 1; i > 0; --i) {
            if (ts[i] > ts[i-1]) {
              float tf = ts[i]; ts[i] = ts[i-1]; ts[i-1] = tf;
              int   tx = ti[i]; ti[i] = ti[i-1]; ti[i-1] = tx;
            }
          }
        }
      }
    }
  }
  #undef LOADT
  if (l < 32) {
    int row = rowbase + l;
    #pragma unroll
    for (int i = 0; i < NC; ++i) part[(size_t)row * (NSEG * NC) + seg * NC + i] = ti[i];
  }
}

// ---------------- stage 2: exact f64 rescore of 64 candidates -> top-5 ----------------
__global__ __launch_bounds__(64) void k_rescore(const float* __restrict__ Q,
                                                const float* __restrict__ mk,
                                                const double* __restrict__ sq64,
                                                const int* __restrict__ part,
                                                int* __restrict__ idx5) {
  const int row = blockIdx.x;
  const int l = threadIdx.x;
  const float* Qr = Q + (size_t)row * EE;
  float q[8];
  #pragma unroll
  for (int i = 0; i < 8; ++i) q[i] = Qr[l + 64*i];
  double bs[5] = {-1e300, -1e300, -1e300, -1e300, -1e300};
  int    bi[5] = {0, 0, 0, 0, 0};
  for (int c = 0; c < NSEG * NC; ++c) {
    int idx = part[(size_t)row * (NSEG * NC) + c];
    const float* kr = mk + (size_t)idx * EE;
    double p = 0.0;
    #pragma unroll
    for (int i = 0; i < 8; ++i) p += (double)q[i] * (double)kr[l + 64*i];
    #pragma unroll
    for (int o = 32; o > 0; o >>= 1) p += __shfl_down(p, o);
    if (l == 0) {
      double s = 2.0 * p - sq64[idx];
      if (s > bs[4]) {
        bs[4] = s; bi[4] = idx;
        #pragma unroll
        for (int i = 4; i > 0; --i) {
          if (bs[i] > bs[i-1]) {
            double tf = bs[i]; bs[i] = bs[i-1]; bs[i-1] = tf;
            int    tx = bi[i]; bi[i] = bi[i-1]; bi[i-1] = tx;
          }
        }
      }
    }
  }
  if (l == 0) {
    #pragma unroll
    for (int i = 0; i < 5; ++i) idx5[(size_t)row*5 + i] = bi[i];
  }
}

// ---------------- exact f32 projection GEMM: out = A(rows) @ B^T + bias (f16 store) ----------------
template <int GATHER>
__global__ __launch_bounds__(256) void k_pgemm(const float* __restrict__ A, const int* __restrict__ gidx,
                                               const float* __restrict__ B, const float* __restrict__ bias,
                                               f16* __restrict__ out) {
  __shared__ float As[64][33];
  __shared__ float Bs[64][33];
  const int m0 = blockIdx.x * 64, n0 = blockIdx.y * 64;
  const int tx = threadIdx.x & 15, ty = threadIdx.x >> 4;
  const int lr = threadIdx.x >> 2;
  const int lc = (threadIdx.x & 3) * 8;
  const float* arow = GATHER ? (A + (size_t)gidx[m0 + lr] * EE) : (A + (size_t)(m0 + lr) * EE);
  const float* brow = B + (size_t)(n0 + lr) * EE;
  float acc[4][4] = {};
  for (int kb = 0; kb < EE; kb += 32) {
    __syncthreads();
    float4 a0 = *(const float4*)(arow + kb + lc);
    float4 a1 = *(const float4*)(arow + kb + lc + 4);
    float4 b0 = *(const float4*)(brow + kb + lc);
    float4 b1 = *(const float4*)(brow + kb + lc + 4);
    As[lr][lc+0]=a0.x; As[lr][lc+1]=a0.y; As[lr][lc+2]=a0.z; As[lr][lc+3]=a0.w;
    As[lr][lc+4]=a1.x; As[lr][lc+5]=a1.y; As[lr][lc+6]=a1.z; As[lr][lc+7]=a1.w;
    Bs[lr][lc+0]=b0.x; Bs[lr][lc+1]=b0.y; Bs[lr][lc+2]=b0.z; Bs[lr][lc+3]=b0.w;
    Bs[lr][lc+4]=b1.x; Bs[lr][lc+5]=b1.y; Bs[lr][lc+6]=b1.z; Bs[lr][lc+7]=b1.w;
    __syncthreads();
    #pragma unroll
    for (int t = 0; t < 32; ++t) {
      float av[4], bv[4];
      #pragma unroll
      for (int u = 0; u < 4; ++u) av[u] = As[ty*4+u][t];
      #pragma unroll
      for (int u = 0; u < 4; ++u) bv[u] = Bs[tx*4+u][t];
      #pragma unroll
      for (int a = 0; a < 4; ++a)
        #pragma unroll
        for (int b = 0; b < 4; ++b) acc[a][b] = fmaf(av[a], bv[b], acc[a][b]);
    }
  }
  #pragma unroll
  for (int a = 0; a < 4; ++a)
    #pragma unroll
    for (int b = 0; b < 4; ++b)
      out[(size_t)(m0 + ty*4 + a) * EE + n0 + tx*4 + b] = (f16)(acc[a][b] + bias[n0 + tx*4 + b]);
}

// ---------------- final: out = ao @ Wout^T + bo, f32 store (reference output dtype) ----------------
__global__ __launch_bounds__(256) void k_pgemm_out(const f16* __restrict__ A, const float* __restrict__ B,
                                                   const float* __restrict__ bias,
                                                   float* __restrict__ out) {
  __shared__ float As[64][33];
  __shared__ float Bs[64][33];
  const int m0 = blockIdx.x * 64, n0 = blockIdx.y * 64;
  const int tx = threadIdx.x & 15, ty = threadIdx.x >> 4;
  const int lr = threadIdx.x >> 2;
  const int lc = (threadIdx.x & 3) * 8;
  const f16*   arow = A + (size_t)(m0 + lr) * EE;
  const float* brow = B + (size_t)(n0 + lr) * EE;
  float acc[4][4] = {};
  for (int kb = 0; kb < EE; kb += 32) {
    __syncthreads();
    f16x8 av8 = *(const f16x8*)(arow + kb + lc);
    float4 b0 = *(const float4*)(brow + kb + lc);
    float4 b1 = *(const float4*)(brow + kb + lc + 4);
    #pragma unroll
    for (int i = 0; i < 8; ++i) As[lr][lc+i] = (float)av8[i];
    Bs[lr][lc+0]=b0.x; Bs[lr][lc+1]=b0.y; Bs[lr][lc+2]=b0.z; Bs[lr][lc+3]=b0.w;
    Bs[lr][lc+4]=b1.x; Bs[lr][lc+5]=b1.y; Bs[lr][lc+6]=b1.z; Bs[lr][lc+7]=b1.w;
    __syncthreads();
    #pragma unroll
    for (int t = 0; t < 32; ++t) {
      float av[4], bv[4];
      #pragma unroll
      for (int u = 0; u < 4; ++u) av[u] = As[ty*4+u][t];
      #pragma unroll
      for (int u = 0; u < 4; ++u) bv[u] = Bs[tx*4+u][t];
      #pragma unroll
      for (int a = 0; a < 4; ++a)
        #pragma unroll
        for (int b = 0; b < 4; ++b) acc[a][b] = fmaf(av[a], bv[b], acc[a][b]);
    }
  }
  #pragma unroll
  for (int a = 0; a < 4; ++a)
    #pragma unroll
    for (int b = 0; b < 4; ++b)
      out[(size_t)(m0 + ty*4 + a) * EE + n0 + tx*4 + b] = acc[a][b] + bias[n0 + tx*4 + b];
}

// ---------------- 5-key MHA (H=8, d=64), f32 compute ----------------
__global__ __launch_bounds__(256) void k_attn(const f16* __restrict__ qp, const f16* __restrict__ kp,
                                              const f16* __restrict__ vp, f16* __restrict__ ao) {
  int row = blockIdx.x * 4 + (threadIdx.x >> 6);
  int l = threadIdx.x & 63;
  int h = l >> 3, sl = l & 7;
  const f16* q = qp + (size_t)row * EE + h * 64 + sl * 8;
  float qv[8];
  #pragma unroll
  for (int i = 0; i < 8; ++i) qv[i] = (float)q[i];
  float sc[5];
  #pragma unroll
  for (int j = 0; j < 5; ++j) {
    const f16* kr = kp + ((size_t)row * 5 + j) * EE + h * 64 + sl * 8;
    float p = 0.f;
    #pragma unroll
    for (int i = 0; i < 8; ++i) p = fmaf(qv[i], (float)kr[i], p);
    p += __shfl_xor(p, 1); p += __shfl_xor(p, 2); p += __shfl_xor(p, 4);
    sc[j] = p * 0.125f;
  }
  float mx = fmaxf(fmaxf(fmaxf(sc[0], sc[1]), fmaxf(sc[2], sc[3])), sc[4]);
  float sum = 0.f;
  #pragma unroll
  for (int j = 0; j < 5; ++j) { sc[j] = __expf(sc[j] - mx); sum += sc[j]; }
  float inv = 1.0f / sum;
  float o[8] = {};
  #pragma unroll
  for (int j = 0; j < 5; ++j) {
    const f16* vr = vp + ((size_t)row * 5 + j) * EE + h * 64 + sl * 8;
    float aw = sc[j] * inv;
    #pragma unroll
    for (int i = 0; i < 8; ++i) o[i] = fmaf(aw, (float)vr[i], o[i]);
  }
  f16* dst = ao + (size_t)row * EE + h * 64 + sl * 8;
  #pragma unroll
  for (int i = 0; i < 8; ++i) dst[i] = (f16)o[i];
}

extern "C" void kernel_launch(void* const* d_in, const int* in_sizes, int n_in,
                              void* d_out, int out_size, void* d_ws, size_t ws_size,
                              hipStream_t stream) {
  const float* Q    = (const float*)d_in[0];
  const float* mk   = (const float*)d_in[1];
  const float* mv   = (const float*)d_in[2];
  const float* Wq   = (const float*)d_in[3];
  const float* bq   = (const float*)d_in[4];
  const float* Wk   = (const float*)d_in[5];
  const float* bk   = (const float*)d_in[6];
  const float* Wv   = (const float*)d_in[7];
  const float* bv   = (const float*)d_in[8];
  const float* Wiq  = (const float*)d_in[9];
  const float* Wik  = (const float*)d_in[10];
  const float* Wiv  = (const float*)d_in[11];
  const float* b_in = (const float*)d_in[12];
  const float* Wo   = (const float*)d_in[13];
  const float* bo   = (const float*)d_in[14];

  char* w = (char*)d_ws;
  size_t off = 0;
  auto alloc = [&](size_t bytes) { size_t o = off; off += (bytes + 255) & ~(size_t)255; return o; };
  f16*    Kh   = (f16*)(w + alloc((size_t)NMEM * EE * 2));   // dead after stage1 -> reused as kp
  f16*    Qh   = (f16*)(w + alloc((size_t)BQ * EE * 2));
  float*  sq32 = (float*)(w + alloc((size_t)NMEM * 4));
  double* sq64 = (double*)(w + alloc((size_t)NMEM * 8));
  float*  Wc   = (float*)(w + alloc((size_t)3 * EE * EE * 4));
  float*  bc   = (float*)(w + alloc((size_t)3 * EE * 4));
  int*    part = (int*)(w + alloc((size_t)BQ * NSEG * NC * 4));
  int*    idx5 = (int*)(w + alloc((size_t)BQ * 5 * 4));
  f16*    qp   = (f16*)(w + alloc((size_t)BQ * EE * 2));
  f16*    vp   = (f16*)(w + alloc((size_t)BQ * 5 * EE * 2));
  f16*    ao   = (f16*)(w + alloc((size_t)BQ * EE * 2));
  f16*    kp   = Kh;  // overlay: BQ*5*EE*2 = 41.9MB <= Kh's 51.2MB, Kh dead by then
  (void)ws_size; (void)in_sizes; (void)n_in; (void)out_size;

  k_prep_keys<<<NMEM / 4, 256, 0, stream>>>(mk, Kh, sq32, sq64);
  k_prep_q<<<BQ / 4, 256, 0, stream>>>(Q, Qh);
  k_compose<<<dim3(8, 8, 3), 256, 0, stream>>>(Wq, Wk, Wv, Wiq, Wik, Wiv, Wc);
  k_bias<<<3, 256, 0, stream>>>(Wiq, Wik, Wiv, bq, bk, bv, b_in, bc);
  k_stage1<<<dim3(BQ / 256, NSEG), 512, 0, stream>>>(Qh, Kh, sq32, part);
  k_rescore<<<BQ, 64, 0, stream>>>(Q, mk, sq64, part, idx5);
  k_pgemm<0><<<dim3(BQ / 64, 8), 256, 0, stream>>>(Q, nullptr, Wc, bc, qp);
  k_pgemm<1><<<dim3(BQ * 5 / 64, 8), 256, 0, stream>>>(mk, idx5, Wc + (size_t)EE * EE, bc + EE, kp);
  k_pgemm<1><<<dim3(BQ * 5 / 64, 8), 256, 0, stream>>>(mv, idx5, Wc + (size_t)2 * EE * EE, bc + 2 * EE, vp);
  k_attn<<<BQ / 4, 256, 0, stream>>>(qp, kp, vp, ao);
  k_pgemm_out<<<dim3(BQ / 64, 8), 256, 0, stream>>>(ao, Wo, bo, (float*)d_out);
}

// Round 5
// 1251.279 us; speedup vs baseline: 1.7428x; 1.7428x over previous
//
#include <hip/hip_runtime.h>
#include <hip/hip_bf16.h>
#include <hip/hip_fp16.h>

typedef _Float16 f16;
typedef _Float16 f16x8 __attribute__((ext_vector_type(8)));
typedef float f32x4 __attribute__((ext_vector_type(4)));

constexpr int EE     = 512;
constexpr int NMEM   = 50000;
constexpr int BQ     = 8192;
constexpr int NSEG   = 16;
constexpr int SEGLEN = (NMEM + NSEG - 1) / NSEG;   // 3125
constexpr int NT     = (SEGLEN + 15) / 16;          // 196
constexpr int NC     = 6;                           // candidates kept per segment

// ---------------- prep: f32 -> fp16 keys + f64/f32 row norms ----------------
__global__ __launch_bounds__(256) void k_prep_keys(const float* __restrict__ mk,
                                                   f16* __restrict__ kh,
                                                   float* __restrict__ sq32,
                                                   double* __restrict__ sq64) {
  int row  = blockIdx.x * 4 + (threadIdx.x >> 6);
  int lane = threadIdx.x & 63;
  const float4* src = (const float4*)(mk + (size_t)row * EE) + lane * 2;
  float4 a = src[0], b = src[1];
  double s = (double)a.x*a.x + (double)a.y*a.y + (double)a.z*a.z + (double)a.w*a.w
           + (double)b.x*b.x + (double)b.y*b.y + (double)b.z*b.z + (double)b.w*b.w;
  f16x8 h;
  h[0]=(f16)a.x; h[1]=(f16)a.y; h[2]=(f16)a.z; h[3]=(f16)a.w;
  h[4]=(f16)b.x; h[5]=(f16)b.y; h[6]=(f16)b.z; h[7]=(f16)b.w;
  *((f16x8*)(kh + (size_t)row * EE) + lane) = h;
  #pragma unroll
  for (int o = 32; o > 0; o >>= 1) s += __shfl_down(s, o);
  if (lane == 0) { sq64[row] = s; sq32[row] = (float)s; }
}

__global__ __launch_bounds__(256) void k_prep_q(const float* __restrict__ Q,
                                                f16* __restrict__ qh) {
  int row  = blockIdx.x * 4 + (threadIdx.x >> 6);
  int lane = threadIdx.x & 63;
  const float4* src = (const float4*)(Q + (size_t)row * EE) + lane * 2;
  float4 a = src[0], b = src[1];
  f16x8 h;
  h[0]=(f16)a.x; h[1]=(f16)a.y; h[2]=(f16)a.z; h[3]=(f16)a.w;
  h[4]=(f16)b.x; h[5]=(f16)b.y; h[6]=(f16)b.z; h[7]=(f16)b.w;
  *((f16x8*)(qh + (size_t)row * EE) + lane) = h;
}

// ---------------- compose weights: Wc_m = Win_m @ W_m (f32 acc -> fp16 out) ----------------
__global__ __launch_bounds__(256) void k_compose(const float* __restrict__ Wq, const float* __restrict__ Wk,
                                                 const float* __restrict__ Wv, const float* __restrict__ Wiq,
                                                 const float* __restrict__ Wik, const float* __restrict__ Wiv,
                                                 f16* __restrict__ Wc) {
  int m = blockIdx.z;
  const float* A = (m == 0) ? Wiq : ((m == 1) ? Wik : Wiv);
  const float* B = (m == 0) ? Wq  : ((m == 1) ? Wk  : Wv);
  f16* C = Wc + (size_t)m * EE * EE;
  __shared__ float As[64][33];
  __shared__ float Bs[32][65];
  int i0 = blockIdx.x * 64, j0 = blockIdx.y * 64;
  int tx = threadIdx.x & 15, ty = threadIdx.x >> 4;
  float acc[4][4] = {};
  for (int kb = 0; kb < EE; kb += 32) {
    __syncthreads();
    #pragma unroll
    for (int v = 0; v < 8; ++v) {
      int idx = threadIdx.x + v * 256;
      As[idx >> 5][idx & 31] = A[(size_t)(i0 + (idx >> 5)) * EE + kb + (idx & 31)];
    }
    #pragma unroll
    for (int v = 0; v < 8; ++v) {
      int idx = threadIdx.x + v * 256;
      Bs[idx >> 6][idx & 63] = B[(size_t)(kb + (idx >> 6)) * EE + j0 + (idx & 63)];
    }
    __syncthreads();
    for (int t = 0; t < 32; ++t) {
      float av[4], bv[4];
      #pragma unroll
      for (int u = 0; u < 4; ++u) av[u] = As[ty*4+u][t];
      #pragma unroll
      for (int u = 0; u < 4; ++u) bv[u] = Bs[t][tx*4+u];
      #pragma unroll
      for (int a = 0; a < 4; ++a)
        #pragma unroll
        for (int b = 0; b < 4; ++b) acc[a][b] = fmaf(av[a], bv[b], acc[a][b]);
    }
  }
  #pragma unroll
  for (int a = 0; a < 4; ++a)
    #pragma unroll
    for (int b = 0; b < 4; ++b)
      C[(size_t)(i0 + ty*4 + a) * EE + j0 + tx*4 + b] = (f16)acc[a][b];
}

__global__ void k_bias(const float* __restrict__ Wiq, const float* __restrict__ Wik,
                       const float* __restrict__ Wiv, const float* __restrict__ bqv,
                       const float* __restrict__ bkv, const float* __restrict__ bvv,
                       const float* __restrict__ b_in, float* __restrict__ bc) {
  int m = blockIdx.x;
  const float* Wi = (m == 0) ? Wiq : ((m == 1) ? Wik : Wiv);
  const float* bb = (m == 0) ? bqv : ((m == 1) ? bkv : bvv);
  for (int i = threadIdx.x; i < EE; i += blockDim.x) {
    float s = 0.f;
    for (int t = 0; t < EE; ++t) s = fmaf(Wi[(size_t)i * EE + t], bb[t], s);
    bc[m * EE + i] = s + b_in[m * EE + i];
  }
}

__global__ void k_cvtw(const float* __restrict__ W, f16* __restrict__ Wo) {
  int i = blockIdx.x * 256 + threadIdx.x;
  Wo[i] = (f16)W[i];
}

// ---------------- stage 1: fp16 MFMA scores + per-segment top-6 ----------------
// grid (BQ/256, NSEG) = (32,16) = 512 blocks -> 2 blocks/CU.
// 8 waves x 32 rows; 2 lanes per row each keep sorted top-6 of their 8 cands/tile.
__global__ __launch_bounds__(512, 2) void k_stage1(const f16* __restrict__ Qh,
                                                   const f16* __restrict__ Kh,
                                                   const float* __restrict__ sq32,
                                                   int* __restrict__ part) {
  const int rb  = blockIdx.x;
  const int seg = blockIdx.y;
  const int tid = threadIdx.x;
  const int w   = tid >> 6;
  const int l   = tid & 63;
  const int lc  = l & 15, lp = l >> 4;
  const int seg_start = seg * SEGLEN;

  __shared__ f16   Bt[16 * 520];
  __shared__ float sqs[16];
  __shared__ float scratch[8][32][17];

  const int rowbase = rb * 256 + w * 32;
  f16x8 areg[2][16];
  #pragma unroll
  for (int m = 0; m < 2; ++m)
    #pragma unroll
    for (int ks = 0; ks < 16; ++ks)
      areg[m][ks] = *(const f16x8*)(Qh + (size_t)(rowbase + m*16 + lc) * EE + ks*32 + lp*8);

  float ts[NC]; int ti[NC];
  #pragma unroll
  for (int i = 0; i < NC; ++i) { ts[i] = -3.0e38f; ti[i] = 0; }
  const int hh = l >> 5;        // which half of the 16 candidates this lane scans
  const int rr = l & 31;        // row within wave

  float4 st0, st1; float stsq = 0.f;
  #define LOADT(tt) do { \
      int kk = seg_start + (tt) * 16; \
      int key0 = kk + w; \
      int key1 = key0 + 8; \
      key0 = key0 < NMEM ? key0 : NMEM - 1; \
      key1 = key1 < NMEM ? key1 : NMEM - 1; \
      st0 = *(const float4*)(Kh + (size_t)key0 * EE + l * 8); \
      st1 = *(const float4*)(Kh + (size_t)key1 * EE + l * 8); \
      if (tid < 16) { int kq = kk + tid; stsq = sq32[kq < NMEM ? kq : NMEM - 1]; } \
    } while (0)

  LOADT(0);
  for (int t = 0; t < NT; ++t) {
    __syncthreads();
    *(float4*)&Bt[w * 520 + l * 8]       = st0;
    *(float4*)&Bt[(w + 8) * 520 + l * 8] = st1;
    if (tid < 16) sqs[tid] = stsq;
    __syncthreads();
    if (t + 1 < NT) LOADT(t + 1);

    f32x4 acc0 = {0,0,0,0}, acc1 = {0,0,0,0};
    #pragma unroll
    for (int ks = 0; ks < 16; ++ks) {
      f16x8 b = *(const f16x8*)&Bt[lc * 520 + ks * 32 + lp * 8];
      acc0 = __builtin_amdgcn_mfma_f32_16x16x32_f16(areg[0][ks], b, acc0, 0, 0, 0);
      acc1 = __builtin_amdgcn_mfma_f32_16x16x32_f16(areg[1][ks], b, acc1, 0, 0, 0);
    }
    float myq = sqs[lc];
    #pragma unroll
    for (int r = 0; r < 4; ++r) {
      scratch[w][lp*4 + r][lc]      = 2.0f * acc0[r] - myq;
      scratch[w][16 + lp*4 + r][lc] = 2.0f * acc1[r] - myq;
    }
    int nvalid = SEGLEN - t * 16; if (nvalid > 16) nvalid = 16;
    #pragma unroll
    for (int c = 0; c < 8; ++c) {
      int ci = hh * 8 + c;
      if (ci < nvalid) {
        float s = scratch[w][rr][ci];
        if (s > ts[NC-1]) {
          ts[NC-1] = s; ti[NC-1] = seg_start + t * 16 + ci;
          #pragma unroll
          for (int i = NC - 1; i > 0; --i) {
            if (ts[i] > ts[i-1]) {
              float tf = ts[i]; ts[i] = ts[i-1]; ts[i-1] = tf;
              int   tx = ti[i]; ti[i] = ti[i-1]; ti[i-1] = tx;
            }
          }
        }
      }
    }
  }
  #undef LOADT

  // merge lane pair (l, l^32): insert partner's sorted list into ours (static indices only)
  float ots[NC]; int oti[NC];
  #pragma unroll
  for (int i = 0; i < NC; ++i) {
    ots[i] = __shfl_xor(ts[i], 32);
    oti[i] = __shfl_xor(ti[i], 32);
  }
  if (l < 32) {
    #pragma unroll
    for (int j = 0; j < NC; ++j) {
      float s = ots[j]; int x = oti[j];
      if (s > ts[NC-1]) {
        ts[NC-1] = s; ti[NC-1] = x;
        #pragma unroll
        for (int i = NC - 1; i > 0; --i) {
          if (ts[i] > ts[i-1]) {
            float tf = ts[i]; ts[i] = ts[i-1]; ts[i-1] = tf;
            int   tx = ti[i]; ti[i] = ti[i-1]; ti[i-1] = tx;
          }
        }
      }
    }
    int row = rowbase + l;
    #pragma unroll
    for (int i = 0; i < NC; ++i) part[(size_t)row * (NSEG * NC) + seg * NC + i] = ti[i];
  }
}

// ---------------- stage 2: exact f64 rescore of 96 candidates -> top-5 ----------------
__global__ __launch_bounds__(64) void k_rescore(const float* __restrict__ Q,
                                                const float* __restrict__ mk,
                                                const double* __restrict__ sq64,
                                                const int* __restrict__ part,
                                                int* __restrict__ idx5) {
  const int row = blockIdx.x;
  const int l = threadIdx.x;
  const float* Qr = Q + (size_t)row * EE;
  float q[8];
  #pragma unroll
  for (int i = 0; i < 8; ++i) q[i] = Qr[l + 64*i];
  double bs[5] = {-1e300, -1e300, -1e300, -1e300, -1e300};
  int    bi[5] = {0, 0, 0, 0, 0};
  for (int c = 0; c < NSEG * NC; ++c) {
    int idx = part[(size_t)row * (NSEG * NC) + c];
    const float* kr = mk + (size_t)idx * EE;
    double p = 0.0;
    #pragma unroll
    for (int i = 0; i < 8; ++i) p += (double)q[i] * (double)kr[l + 64*i];
    #pragma unroll
    for (int o = 32; o > 0; o >>= 1) p += __shfl_down(p, o);
    if (l == 0) {
      double s = 2.0 * p - sq64[idx];
      if (s > bs[4]) {
        bs[4] = s; bi[4] = idx;
        #pragma unroll
        for (int i = 4; i > 0; --i) {
          if (bs[i] > bs[i-1]) {
            double tf = bs[i]; bs[i] = bs[i-1]; bs[i-1] = tf;
            int    tx = bi[i]; bi[i] = bi[i-1]; bi[i-1] = tx;
          }
        }
      }
    }
  }
  if (l == 0) {
    #pragma unroll
    for (int i = 0; i < 5; ++i) idx5[(size_t)row*5 + i] = bi[i];
  }
}

// ---------------- fp16 MFMA GEMM: C = A @ B^T + bias (64x64 tile) ----------------
template <int OUTF32>
__global__ __launch_bounds__(256) void k_gemm(const f16* __restrict__ A, const f16* __restrict__ B,
                                              const float* __restrict__ bias, void* __restrict__ outp) {
  __shared__ f16 As[64][72];
  __shared__ f16 Bs[64][72];
  const int tid = threadIdx.x;
  const int wv = tid >> 6, l = tid & 63, lc = l & 15, lp = l >> 4;
  const int m0 = blockIdx.x * 64, n0 = blockIdx.y * 64;
  const int r = tid >> 2, co = (tid & 3) * 16;
  f32x4 acc[4] = {{0,0,0,0},{0,0,0,0},{0,0,0,0},{0,0,0,0}};
  for (int kb = 0; kb < EE; kb += 64) {
    __syncthreads();
    *(float4*)&As[r][co]     = *(const float4*)(A + (size_t)(m0 + r) * EE + kb + co);
    *(float4*)&As[r][co + 8] = *(const float4*)(A + (size_t)(m0 + r) * EE + kb + co + 8);
    *(float4*)&Bs[r][co]     = *(const float4*)(B + (size_t)(n0 + r) * EE + kb + co);
    *(float4*)&Bs[r][co + 8] = *(const float4*)(B + (size_t)(n0 + r) * EE + kb + co + 8);
    __syncthreads();
    #pragma unroll
    for (int ks = 0; ks < 2; ++ks) {
      f16x8 a = *(const f16x8*)&As[wv*16 + lc][ks*32 + lp*8];
      #pragma unroll
      for (int f = 0; f < 4; ++f) {
        f16x8 b = *(const f16x8*)&Bs[f*16 + lc][ks*32 + lp*8];
        acc[f] = __builtin_amdgcn_mfma_f32_16x16x32_f16(a, b, acc[f], 0, 0, 0);
      }
    }
  }
  #pragma unroll
  for (int f = 0; f < 4; ++f) {
    int col = n0 + f*16 + lc;
    float bsv = bias[col];
    #pragma unroll
    for (int rr = 0; rr < 4; ++rr) {
      int row = m0 + wv*16 + lp*4 + rr;
      float v = acc[f][rr] + bsv;
      if (OUTF32) ((float*)outp)[(size_t)row * EE + col] = v;
      else        ((f16*)outp)[(size_t)row * EE + col] = (f16)v;
    }
  }
}

// gather variant: A rows from mem[idx[row]] (f32 -> fp16 inline)
__global__ __launch_bounds__(256) void k_gemm_g(const int* __restrict__ gidx, const float* __restrict__ Asrc,
                                                const f16* __restrict__ B, const float* __restrict__ bias,
                                                f16* __restrict__ outp) {
  __shared__ f16 As[64][72];
  __shared__ f16 Bs[64][72];
  const int tid = threadIdx.x;
  const int wv = tid >> 6, l = tid & 63, lc = l & 15, lp = l >> 4;
  const int m0 = blockIdx.x * 64, n0 = blockIdx.y * 64;
  const int r = tid >> 2, co = (tid & 3) * 16;
  const int gi = gidx[m0 + r];
  const float* arow = Asrc + (size_t)gi * EE;
  f32x4 acc[4] = {{0,0,0,0},{0,0,0,0},{0,0,0,0},{0,0,0,0}};
  for (int kb = 0; kb < EE; kb += 64) {
    __syncthreads();
    float4 x0 = *(const float4*)(arow + kb + co);
    float4 x1 = *(const float4*)(arow + kb + co + 4);
    float4 x2 = *(const float4*)(arow + kb + co + 8);
    float4 x3 = *(const float4*)(arow + kb + co + 12);
    f16x8 h0, h1;
    h0[0]=(f16)x0.x; h0[1]=(f16)x0.y; h0[2]=(f16)x0.z; h0[3]=(f16)x0.w;
    h0[4]=(f16)x1.x; h0[5]=(f16)x1.y; h0[6]=(f16)x1.z; h0[7]=(f16)x1.w;
    h1[0]=(f16)x2.x; h1[1]=(f16)x2.y; h1[2]=(f16)x2.z; h1[3]=(f16)x2.w;
    h1[4]=(f16)x3.x; h1[5]=(f16)x3.y; h1[6]=(f16)x3.z; h1[7]=(f16)x3.w;
    *(f16x8*)&As[r][co]     = h0;
    *(f16x8*)&As[r][co + 8] = h1;
    *(float4*)&Bs[r][co]     = *(const float4*)(B + (size_t)(n0 + r) * EE + kb + co);
    *(float4*)&Bs[r][co + 8] = *(const float4*)(B + (size_t)(n0 + r) * EE + kb + co + 8);
    __syncthreads();
    #pragma unroll
    for (int ks = 0; ks < 2; ++ks) {
      f16x8 a = *(const f16x8*)&As[wv*16 + lc][ks*32 + lp*8];
      #pragma unroll
      for (int f = 0; f < 4; ++f) {
        f16x8 b = *(const f16x8*)&Bs[f*16 + lc][ks*32 + lp*8];
        acc[f] = __builtin_amdgcn_mfma_f32_16x16x32_f16(a, b, acc[f], 0, 0, 0);
      }
    }
  }
  #pragma unroll
  for (int f = 0; f < 4; ++f) {
    int col = n0 + f*16 + lc;
    float bsv = bias[col];
    #pragma unroll
    for (int rr = 0; rr < 4; ++rr) {
      int row = m0 + wv*16 + lp*4 + rr;
      outp[(size_t)row * EE + col] = (f16)(acc[f][rr] + bsv);
    }
  }
}

// ---------------- 5-key MHA (H=8, d=64), f32 compute ----------------
__global__ __launch_bounds__(256) void k_attn(const f16* __restrict__ qp, const f16* __restrict__ kp,
                                              const f16* __restrict__ vp, f16* __restrict__ ao) {
  int row = blockIdx.x * 4 + (threadIdx.x >> 6);
  int l = threadIdx.x & 63;
  int h = l >> 3, sl = l & 7;
  const f16* q = qp + (size_t)row * EE + h * 64 + sl * 8;
  float qv[8];
  #pragma unroll
  for (int i = 0; i < 8; ++i) qv[i] = (float)q[i];
  float sc[5];
  #pragma unroll
  for (int j = 0; j < 5; ++j) {
    const f16* kr = kp + ((size_t)row * 5 + j) * EE + h * 64 + sl * 8;
    float p = 0.f;
    #pragma unroll
    for (int i = 0; i < 8; ++i) p = fmaf(qv[i], (float)kr[i], p);
    p += __shfl_xor(p, 1); p += __shfl_xor(p, 2); p += __shfl_xor(p, 4);
    sc[j] = p * 0.125f;
  }
  float mx = fmaxf(fmaxf(fmaxf(sc[0], sc[1]), fmaxf(sc[2], sc[3])), sc[4]);
  float sum = 0.f;
  #pragma unroll
  for (int j = 0; j < 5; ++j) { sc[j] = __expf(sc[j] - mx); sum += sc[j]; }
  float inv = 1.0f / sum;
  float o[8] = {};
  #pragma unroll
  for (int j = 0; j < 5; ++j) {
    const f16* vr = vp + ((size_t)row * 5 + j) * EE + h * 64 + sl * 8;
    float aw = sc[j] * inv;
    #pragma unroll
    for (int i = 0; i < 8; ++i) o[i] = fmaf(aw, (float)vr[i], o[i]);
  }
  f16* dst = ao + (size_t)row * EE + h * 64 + sl * 8;
  #pragma unroll
  for (int i = 0; i < 8; ++i) dst[i] = (f16)o[i];
}

extern "C" void kernel_launch(void* const* d_in, const int* in_sizes, int n_in,
                              void* d_out, int out_size, void* d_ws, size_t ws_size,
                              hipStream_t stream) {
  const float* Q    = (const float*)d_in[0];
  const float* mk   = (const float*)d_in[1];
  const float* mv   = (const float*)d_in[2];
  const float* Wq   = (const float*)d_in[3];
  const float* bq   = (const float*)d_in[4];
  const float* Wk   = (const float*)d_in[5];
  const float* bk   = (const float*)d_in[6];
  const float* Wv   = (const float*)d_in[7];
  const float* bv   = (const float*)d_in[8];
  const float* Wiq  = (const float*)d_in[9];
  const float* Wik  = (const float*)d_in[10];
  const float* Wiv  = (const float*)d_in[11];
  const float* b_in = (const float*)d_in[12];
  const float* Wo   = (const float*)d_in[13];
  const float* bo   = (const float*)d_in[14];

  char* w = (char*)d_ws;
  size_t off = 0;
  auto alloc = [&](size_t bytes) { size_t o = off; off += (bytes + 255) & ~(size_t)255; return o; };
  f16*    Kh   = (f16*)(w + alloc((size_t)NMEM * EE * 2));   // dead after stage1 -> reused as kp
  f16*    Qh   = (f16*)(w + alloc((size_t)BQ * EE * 2));
  float*  sq32 = (float*)(w + alloc((size_t)NMEM * 4));
  double* sq64 = (double*)(w + alloc((size_t)NMEM * 8));
  f16*    Wc   = (f16*)(w + alloc((size_t)3 * EE * EE * 2));
  f16*    Wo16 = (f16*)(w + alloc((size_t)EE * EE * 2));
  float*  bc   = (float*)(w + alloc((size_t)3 * EE * 4));
  int*    part = (int*)(w + alloc((size_t)BQ * NSEG * NC * 4));
  int*    idx5 = (int*)(w + alloc((size_t)BQ * 5 * 4));
  f16*    qp   = (f16*)(w + alloc((size_t)BQ * EE * 2));
  f16*    vp   = (f16*)(w + alloc((size_t)BQ * 5 * EE * 2));
  f16*    ao   = (f16*)(w + alloc((size_t)BQ * EE * 2));
  f16*    kp   = Kh;  // overlay: BQ*5*EE*2 = 41.9MB <= Kh's 51.2MB, Kh dead by then
  (void)ws_size; (void)in_sizes; (void)n_in; (void)out_size;

  k_prep_keys<<<NMEM / 4, 256, 0, stream>>>(mk, Kh, sq32, sq64);
  k_prep_q<<<BQ / 4, 256, 0, stream>>>(Q, Qh);
  k_compose<<<dim3(8, 8, 3), 256, 0, stream>>>(Wq, Wk, Wv, Wiq, Wik, Wiv, Wc);
  k_bias<<<3, 256, 0, stream>>>(Wiq, Wik, Wiv, bq, bk, bv, b_in, bc);
  k_cvtw<<<(EE * EE) / 256, 256, 0, stream>>>(Wo, Wo16);
  k_stage1<<<dim3(BQ / 256, NSEG), 512, 0, stream>>>(Qh, Kh, sq32, part);
  k_rescore<<<BQ, 64, 0, stream>>>(Q, mk, sq64, part, idx5);
  k_gemm<0><<<dim3(BQ / 64, 8), 256, 0, stream>>>(Qh, Wc, bc, qp);
  k_gemm_g<<<dim3(BQ * 5 / 64, 8), 256, 0, stream>>>(idx5, mk, Wc + (size_t)EE * EE, bc + EE, kp);
  k_gemm_g<<<dim3(BQ * 5 / 64, 8), 256, 0, stream>>>(idx5, mv, Wc + (size_t)2 * EE * EE, bc + 2 * EE, vp);
  k_attn<<<BQ / 4, 256, 0, stream>>>(qp, kp, vp, ao);
  k_gemm<1><<<dim3(BQ / 64, 8), 256, 0, stream>>>(ao, Wo16, bo, (float*)d_out);
}

// Round 7
// 965.690 us; speedup vs baseline: 2.2582x; 1.2957x over previous
//
#include <hip/hip_runtime.h>
#include <hip/hip_bf16.h>
#include <hip/hip_fp16.h>

typedef _Float16 f16;
typedef _Float16 f16x8 __attribute__((ext_vector_type(8)));
typedef float f32x4 __attribute__((ext_vector_type(4)));

constexpr int EE     = 512;
constexpr int NMEM   = 50000;
constexpr int BQ     = 8192;
constexpr int NSEG   = 16;
constexpr int SEGLEN = NMEM / NSEG;        // 3125 (exact)
constexpr int NT     = (SEGLEN + 15) / 16; // 196
constexpr int NC     = 6;                  // candidates kept per segment
constexpr int NCAND  = NSEG * NC;          // 96
constexpr int NRES   = 12;                 // exact-rescored candidates

// ---------------- prep: f32 -> fp16 keys + f64/f32 row norms ----------------
__global__ __launch_bounds__(256) void k_prep_keys(const float* __restrict__ mk,
                                                   f16* __restrict__ kh,
                                                   float* __restrict__ sq32,
                                                   double* __restrict__ sq64) {
  int row  = blockIdx.x * 4 + (threadIdx.x >> 6);
  int lane = threadIdx.x & 63;
  const float4* src = (const float4*)(mk + (size_t)row * EE) + lane * 2;
  float4 a = src[0], b = src[1];
  double s = (double)a.x*a.x + (double)a.y*a.y + (double)a.z*a.z + (double)a.w*a.w
           + (double)b.x*b.x + (double)b.y*b.y + (double)b.z*b.z + (double)b.w*b.w;
  f16x8 h;
  h[0]=(f16)a.x; h[1]=(f16)a.y; h[2]=(f16)a.z; h[3]=(f16)a.w;
  h[4]=(f16)b.x; h[5]=(f16)b.y; h[6]=(f16)b.z; h[7]=(f16)b.w;
  *((f16x8*)(kh + (size_t)row * EE) + lane) = h;
  #pragma unroll
  for (int o = 32; o > 0; o >>= 1) s += __shfl_down(s, o);
  if (lane == 0) { sq64[row] = s; sq32[row] = (float)s; }
}

// generic f32 -> f16 row copy (rows of EE)
__global__ __launch_bounds__(256) void k_prep_f16(const float* __restrict__ src,
                                                  f16* __restrict__ dst) {
  int row  = blockIdx.x * 4 + (threadIdx.x >> 6);
  int lane = threadIdx.x & 63;
  const float4* s = (const float4*)(src + (size_t)row * EE) + lane * 2;
  float4 a = s[0], b = s[1];
  f16x8 h;
  h[0]=(f16)a.x; h[1]=(f16)a.y; h[2]=(f16)a.z; h[3]=(f16)a.w;
  h[4]=(f16)b.x; h[5]=(f16)b.y; h[6]=(f16)b.z; h[7]=(f16)b.w;
  *((f16x8*)(dst + (size_t)row * EE) + lane) = h;
}

// ---------------- compose weights: Wc_m = Win_m @ W_m (f32 acc -> fp16 out) ----------------
__global__ __launch_bounds__(256) void k_compose(const float* __restrict__ Wq, const float* __restrict__ Wk,
                                                 const float* __restrict__ Wv, const float* __restrict__ Wiq,
                                                 const float* __restrict__ Wik, const float* __restrict__ Wiv,
                                                 f16* __restrict__ Wc) {
  int m = blockIdx.z;
  const float* A = (m == 0) ? Wiq : ((m == 1) ? Wik : Wiv);
  const float* B = (m == 0) ? Wq  : ((m == 1) ? Wk  : Wv);
  f16* C = Wc + (size_t)m * EE * EE;
  __shared__ float As[64][33];
  __shared__ float Bs[32][65];
  int i0 = blockIdx.x * 64, j0 = blockIdx.y * 64;
  int tx = threadIdx.x & 15, ty = threadIdx.x >> 4;
  float acc[4][4] = {};
  for (int kb = 0; kb < EE; kb += 32) {
    __syncthreads();
    #pragma unroll
    for (int v = 0; v < 8; ++v) {
      int idx = threadIdx.x + v * 256;
      As[idx >> 5][idx & 31] = A[(size_t)(i0 + (idx >> 5)) * EE + kb + (idx & 31)];
    }
    #pragma unroll
    for (int v = 0; v < 8; ++v) {
      int idx = threadIdx.x + v * 256;
      Bs[idx >> 6][idx & 63] = B[(size_t)(kb + (idx >> 6)) * EE + j0 + (idx & 63)];
    }
    __syncthreads();
    for (int t = 0; t < 32; ++t) {
      float av[4], bv[4];
      #pragma unroll
      for (int u = 0; u < 4; ++u) av[u] = As[ty*4+u][t];
      #pragma unroll
      for (int u = 0; u < 4; ++u) bv[u] = Bs[t][tx*4+u];
      #pragma unroll
      for (int a = 0; a < 4; ++a)
        #pragma unroll
        for (int b = 0; b < 4; ++b) acc[a][b] = fmaf(av[a], bv[b], acc[a][b]);
    }
  }
  #pragma unroll
  for (int a = 0; a < 4; ++a)
    #pragma unroll
    for (int b = 0; b < 4; ++b)
      C[(size_t)(i0 + ty*4 + a) * EE + j0 + tx*4 + b] = (f16)acc[a][b];
}

__global__ void k_bias(const float* __restrict__ Wiq, const float* __restrict__ Wik,
                       const float* __restrict__ Wiv, const float* __restrict__ bqv,
                       const float* __restrict__ bkv, const float* __restrict__ bvv,
                       const float* __restrict__ b_in, float* __restrict__ bc) {
  int m = blockIdx.x;
  const float* Wi = (m == 0) ? Wiq : ((m == 1) ? Wik : Wiv);
  const float* bb = (m == 0) ? bqv : ((m == 1) ? bkv : bvv);
  for (int i = threadIdx.x; i < EE; i += blockDim.x) {
    float s = 0.f;
    for (int t = 0; t < EE; ++t) s = fmaf(Wi[(size_t)i * EE + t], bb[t], s);
    bc[m * EE + i] = s + b_in[m * EE + i];
  }
}

__global__ void k_cvtw(const float* __restrict__ W, f16* __restrict__ Wo) {
  int i = blockIdx.x * 256 + threadIdx.x;
  Wo[i] = (f16)W[i];
}

// ---------------- stage 1: fp16 MFMA scores + per-segment top-6 (with scores) ----------------
// Q fragments loaded via inline-asm global_load_dwordx4 ("=v" outputs cannot be
// rematerialized -> guaranteed VGPR-resident across the K-loop).
__global__ __launch_bounds__(512, 2) void k_stage1(const f16* __restrict__ Qh,
                                                   const f16* __restrict__ Kh,
                                                   const float* __restrict__ sq32,
                                                   int* __restrict__ part_i,
                                                   float* __restrict__ part_s) {
  const int rb  = blockIdx.x;
  const int seg = blockIdx.y;
  const int tid = threadIdx.x;
  const int w   = tid >> 6;
  const int l   = tid & 63;
  const int lc  = l & 15, lp = l >> 4;
  const int seg_start = seg * SEGLEN;

  __shared__ f16   Bt[16 * 520];
  __shared__ float sqs[16];
  __shared__ float scratch[8][32][17];

  const int rowbase = rb * 256 + w * 32;
  f16x8 a0[16], a1[16];
  {
    const f16* base0 = Qh + (size_t)(rowbase + lc) * EE + lp * 8;
    const f16* base1 = base0 + (size_t)16 * EE;
    #pragma unroll
    for (int ks = 0; ks < 16; ++ks) {
      asm volatile("global_load_dwordx4 %0, %1, off"
                   : "=v"(a0[ks]) : "v"(base0 + ks * 32) : "memory");
      asm volatile("global_load_dwordx4 %0, %1, off"
                   : "=v"(a1[ks]) : "v"(base1 + ks * 32) : "memory");
    }
    asm volatile("s_waitcnt vmcnt(0)" ::: "memory");
    __builtin_amdgcn_sched_barrier(0);
  }

  float ts[NC]; int ti[NC];
  #pragma unroll
  for (int i = 0; i < NC; ++i) { ts[i] = -3.0e38f; ti[i] = 0; }
  const int hh = l >> 5;        // which half of the 16 candidates this lane scans
  const int rr = l & 31;        // row within wave

  float4 st0, st1; float stsq = 0.f;
  #define LOADT(tt) do { \
      int kk = seg_start + (tt) * 16; \
      int key0 = kk + w; \
      int key1 = key0 + 8; \
      st0 = *(const float4*)(Kh + (size_t)key0 * EE + l * 8); \
      st1 = *(const float4*)(Kh + (size_t)key1 * EE + l * 8); \
      if (tid < 16) stsq = sq32[kk + tid]; \
    } while (0)

  LOADT(0);
  for (int t = 0; t < NT; ++t) {
    __syncthreads();
    *(float4*)&Bt[w * 520 + l * 8]       = st0;
    *(float4*)&Bt[(w + 8) * 520 + l * 8] = st1;
    if (tid < 16) sqs[tid] = stsq;
    __syncthreads();
    if (t + 1 < NT) LOADT(t + 1);

    f32x4 c0a = {0,0,0,0}, c0b = {0,0,0,0}, c1a = {0,0,0,0}, c1b = {0,0,0,0};
    #pragma unroll
    for (int ks = 0; ks < 8; ++ks) {
      f16x8 b0 = *(const f16x8*)&Bt[lc * 520 + ks * 32 + lp * 8];
      f16x8 b1 = *(const f16x8*)&Bt[lc * 520 + (ks + 8) * 32 + lp * 8];
      c0a = __builtin_amdgcn_mfma_f32_16x16x32_f16(a0[ks],     b0, c0a, 0, 0, 0);
      c1a = __builtin_amdgcn_mfma_f32_16x16x32_f16(a1[ks],     b0, c1a, 0, 0, 0);
      c0b = __builtin_amdgcn_mfma_f32_16x16x32_f16(a0[ks + 8], b1, c0b, 0, 0, 0);
      c1b = __builtin_amdgcn_mfma_f32_16x16x32_f16(a1[ks + 8], b1, c1b, 0, 0, 0);
    }
    f32x4 acc0 = c0a + c0b, acc1 = c1a + c1b;
    float myq = sqs[lc];
    #pragma unroll
    for (int r = 0; r < 4; ++r) {
      scratch[w][lp*4 + r][lc]      = 2.0f * acc0[r] - myq;
      scratch[w][16 + lp*4 + r][lc] = 2.0f * acc1[r] - myq;
    }
    int nvalid = SEGLEN - t * 16; if (nvalid > 16) nvalid = 16;
    #pragma unroll
    for (int c = 0; c < 8; ++c) {
      int ci = hh * 8 + c;
      if (ci < nvalid) {
        float s = scratch[w][rr][ci];
        if (s > ts[NC-1]) {
          ts[NC-1] = s; ti[NC-1] = seg_start + t * 16 + ci;
          #pragma unroll
          for (int i = NC - 1; i > 0; --i) {
            if (ts[i] > ts[i-1]) {
              float tf = ts[i]; ts[i] = ts[i-1]; ts[i-1] = tf;
              int   tx = ti[i]; ti[i] = ti[i-1]; ti[i-1] = tx;
            }
          }
        }
      }
    }
  }
  #undef LOADT

  // merge lane pair (l, l^32)
  float ots[NC]; int oti[NC];
  #pragma unroll
  for (int i = 0; i < NC; ++i) {
    ots[i] = __shfl_xor(ts[i], 32);
    oti[i] = __shfl_xor(ti[i], 32);
  }
  if (l < 32) {
    #pragma unroll
    for (int j = 0; j < NC; ++j) {
      float s = ots[j]; int x = oti[j];
      if (s > ts[NC-1]) {
        ts[NC-1] = s; ti[NC-1] = x;
        #pragma unroll
        for (int i = NC - 1; i > 0; --i) {
          if (ts[i] > ts[i-1]) {
            float tf = ts[i]; ts[i] = ts[i-1]; ts[i-1] = tf;
            int   tx = ti[i]; ti[i] = ti[i-1]; ti[i-1] = tx;
          }
        }
      }
    }
    int row = rowbase + l;
    #pragma unroll
    for (int i = 0; i < NC; ++i) {
      part_i[(size_t)row * NCAND + seg * NC + i] = ti[i];
      part_s[(size_t)row * NCAND + seg * NC + i] = ts[i];
    }
  }
}

// ---------------- stage 2: noisy top-12 of 96, exact f64 rescore -> top-5 ----------------
__global__ __launch_bounds__(64) void k_rescore(const float* __restrict__ Q,
                                                const float* __restrict__ mk,
                                                const double* __restrict__ sq64,
                                                const int* __restrict__ part_i,
                                                const float* __restrict__ part_s,
                                                int* __restrict__ idx5) {
  const int row = blockIdx.x;
  const int l = threadIdx.x;
  const float* Qr = Q + (size_t)row * EE;
  float q[8];
  #pragma unroll
  for (int i = 0; i < 8; ++i) q[i] = Qr[l + 64*i];
  // lane l holds candidate l; lanes 0..31 also hold candidate 64+l
  float s0 = part_s[(size_t)row * NCAND + l];
  int   i0 = part_i[(size_t)row * NCAND + l];
  float s1 = (l < 32) ? part_s[(size_t)row * NCAND + 64 + l] : -3.0e38f;
  int   i1 = (l < 32) ? part_i[(size_t)row * NCAND + 64 + l] : 0;

  double bs[5] = {-1e300, -1e300, -1e300, -1e300, -1e300};
  int    bi[5] = {0, 0, 0, 0, 0};
  #pragma unroll
  for (int p = 0; p < NRES; ++p) {
    // wave argmax over remaining noisy scores (deterministic tie-break on code)
    bool pick0 = (s0 >= s1);
    float m  = pick0 ? s0 : s1;
    int   mi = pick0 ? i0 : i1;
    int   code = (l << 1) | (pick0 ? 0 : 1);
    #pragma unroll
    for (int o = 32; o > 0; o >>= 1) {
      float mo = __shfl_xor(m, o);
      int   io = __shfl_xor(mi, o);
      int   co = __shfl_xor(code, o);
      if (mo > m || (mo == m && co < code)) { m = mo; mi = io; code = co; }
    }
    if ((code >> 1) == l) { if (code & 1) s1 = -3.0e38f; else s0 = -3.0e38f; }
    // exact f64 rescore of candidate mi
    const float* kr = mk + (size_t)mi * EE;
    double pd = 0.0;
    #pragma unroll
    for (int i = 0; i < 8; ++i) pd += (double)q[i] * (double)kr[l + 64*i];
    #pragma unroll
    for (int o = 32; o > 0; o >>= 1) pd += __shfl_down(pd, o);
    if (l == 0) {
      double s = 2.0 * pd - sq64[mi];
      if (s > bs[4]) {
        bs[4] = s; bi[4] = mi;
        #pragma unroll
        for (int i = 4; i > 0; --i) {
          if (bs[i] > bs[i-1]) {
            double tf = bs[i]; bs[i] = bs[i-1]; bs[i-1] = tf;
            int    tx = bi[i]; bi[i] = bi[i-1]; bi[i-1] = tx;
          }
        }
      }
    }
  }
  if (l == 0) {
    #pragma unroll
    for (int i = 0; i < 5; ++i) idx5[(size_t)row*5 + i] = bi[i];
  }
}

// ---------------- fp16 MFMA GEMM: C = A @ B^T + bias (64x64 tile) ----------------
template <int OUTF32>
__global__ __launch_bounds__(256) void k_gemm(const f16* __restrict__ A, const f16* __restrict__ B,
                                              const float* __restrict__ bias, void* __restrict__ outp) {
  __shared__ f16 As[64][72];
  __shared__ f16 Bs[64][72];
  const int tid = threadIdx.x;
  const int wv = tid >> 6, l = tid & 63, lc = l & 15, lp = l >> 4;
  const int m0 = blockIdx.x * 64, n0 = blockIdx.y * 64;
  const int r = tid >> 2, co = (tid & 3) * 16;
  f32x4 acc[4] = {{0,0,0,0},{0,0,0,0},{0,0,0,0},{0,0,0,0}};
  for (int kb = 0; kb < EE; kb += 64) {
    __syncthreads();
    *(float4*)&As[r][co]     = *(const float4*)(A + (size_t)(m0 + r) * EE + kb + co);
    *(float4*)&As[r][co + 8] = *(const float4*)(A + (size_t)(m0 + r) * EE + kb + co + 8);
    *(float4*)&Bs[r][co]     = *(const float4*)(B + (size_t)(n0 + r) * EE + kb + co);
    *(float4*)&Bs[r][co + 8] = *(const float4*)(B + (size_t)(n0 + r) * EE + kb + co + 8);
    __syncthreads();
    #pragma unroll
    for (int ks = 0; ks < 2; ++ks) {
      f16x8 a = *(const f16x8*)&As[wv*16 + lc][ks*32 + lp*8];
      #pragma unroll
      for (int f = 0; f < 4; ++f) {
        f16x8 b = *(const f16x8*)&Bs[f*16 + lc][ks*32 + lp*8];
        acc[f] = __builtin_amdgcn_mfma_f32_16x16x32_f16(a, b, acc[f], 0, 0, 0);
      }
    }
  }
  #pragma unroll
  for (int f = 0; f < 4; ++f) {
    int col = n0 + f*16 + lc;
    float bsv = bias[col];
    #pragma unroll
    for (int rr = 0; rr < 4; ++rr) {
      int row = m0 + wv*16 + lp*4 + rr;
      float v = acc[f][rr] + bsv;
      if (OUTF32) ((float*)outp)[(size_t)row * EE + col] = v;
      else        ((f16*)outp)[(size_t)row * EE + col] = (f16)v;
    }
  }
}

// gather variant: A rows from mem[idx[row]]; AF16: A already f16, else f32 -> f16 inline
template <int AF16>
__global__ __launch_bounds__(256) void k_gemm_g(const int* __restrict__ gidx, const void* __restrict__ Asrc,
                                                const f16* __restrict__ B, const float* __restrict__ bias,
                                                f16* __restrict__ outp) {
  __shared__ f16 As[64][72];
  __shared__ f16 Bs[64][72];
  const int tid = threadIdx.x;
  const int wv = tid >> 6, l = tid & 63, lc = l & 15, lp = l >> 4;
  const int m0 = blockIdx.x * 64, n0 = blockIdx.y * 64;
  const int r = tid >> 2, co = (tid & 3) * 16;
  const int gi = gidx[m0 + r];
  f32x4 acc[4] = {{0,0,0,0},{0,0,0,0},{0,0,0,0},{0,0,0,0}};
  for (int kb = 0; kb < EE; kb += 64) {
    __syncthreads();
    if (AF16) {
      const f16* arow = (const f16*)Asrc + (size_t)gi * EE;
      *(f16x8*)&As[r][co]     = *(const f16x8*)(arow + kb + co);
      *(f16x8*)&As[r][co + 8] = *(const f16x8*)(arow + kb + co + 8);
    } else {
      const float* arow = (const float*)Asrc + (size_t)gi * EE;
      float4 x0 = *(const float4*)(arow + kb + co);
      float4 x1 = *(const float4*)(arow + kb + co + 4);
      float4 x2 = *(const float4*)(arow + kb + co + 8);
      float4 x3 = *(const float4*)(arow + kb + co + 12);
      f16x8 h0, h1;
      h0[0]=(f16)x0.x; h0[1]=(f16)x0.y; h0[2]=(f16)x0.z; h0[3]=(f16)x0.w;
      h0[4]=(f16)x1.x; h0[5]=(f16)x1.y; h0[6]=(f16)x1.z; h0[7]=(f16)x1.w;
      h1[0]=(f16)x2.x; h1[1]=(f16)x2.y; h1[2]=(f16)x2.z; h1[3]=(f16)x2.w;
      h1[4]=(f16)x3.x; h1[5]=(f16)x3.y; h1[6]=(f16)x3.z; h1[7]=(f16)x3.w;
      *(f16x8*)&As[r][co]     = h0;
      *(f16x8*)&As[r][co + 8] = h1;
    }
    *(float4*)&Bs[r][co]     = *(const float4*)(B + (size_t)(n0 + r) * EE + kb + co);
    *(float4*)&Bs[r][co + 8] = *(const float4*)(B + (size_t)(n0 + r) * EE + kb + co + 8);
    __syncthreads();
    #pragma unroll
    for (int ks = 0; ks < 2; ++ks) {
      f16x8 a = *(const f16x8*)&As[wv*16 + lc][ks*32 + lp*8];
      #pragma unroll
      for (int f = 0; f < 4; ++f) {
        f16x8 b = *(const f16x8*)&Bs[f*16 + lc][ks*32 + lp*8];
        acc[f] = __builtin_amdgcn_mfma_f32_16x16x32_f16(a, b, acc[f], 0, 0, 0);
      }
    }
  }
  #pragma unroll
  for (int f = 0; f < 4; ++f) {
    int col = n0 + f*16 + lc;
    float bsv = bias[col];
    #pragma unroll
    for (int rr = 0; rr < 4; ++rr) {
      int row = m0 + wv*16 + lp*4 + rr;
      outp[(size_t)row * EE + col] = (f16)(acc[f][rr] + bsv);
    }
  }
}

// ---------------- 5-key MHA (H=8, d=64), f32 compute ----------------
__global__ __launch_bounds__(256) void k_attn(const f16* __restrict__ qp, const f16* __restrict__ kp,
                                              const f16* __restrict__ vp, f16* __restrict__ ao) {
  int row = blockIdx.x * 4 + (threadIdx.x >> 6);
  int l = threadIdx.x & 63;
  int h = l >> 3, sl = l & 7;
  const f16* q = qp + (size_t)row * EE + h * 64 + sl * 8;
  float qv[8];
  #pragma unroll
  for (int i = 0; i < 8; ++i) qv[i] = (float)q[i];
  float sc[5];
  #pragma unroll
  for (int j = 0; j < 5; ++j) {
    const f16* kr = kp + ((size_t)row * 5 + j) * EE + h * 64 + sl * 8;
    float p = 0.f;
    #pragma unroll
    for (int i = 0; i < 8; ++i) p = fmaf(qv[i], (float)kr[i], p);
    p += __shfl_xor(p, 1); p += __shfl_xor(p, 2); p += __shfl_xor(p, 4);
    sc[j] = p * 0.125f;
  }
  float mx = fmaxf(fmaxf(fmaxf(sc[0], sc[1]), fmaxf(sc[2], sc[3])), sc[4]);
  float sum = 0.f;
  #pragma unroll
  for (int j = 0; j < 5; ++j) { sc[j] = __expf(sc[j] - mx); sum += sc[j]; }
  float inv = 1.0f / sum;
  float o[8] = {};
  #pragma unroll
  for (int j = 0; j < 5; ++j) {
    const f16* vr = vp + ((size_t)row * 5 + j) * EE + h * 64 + sl * 8;
    float aw = sc[j] * inv;
    #pragma unroll
    for (int i = 0; i < 8; ++i) o[i] = fmaf(aw, (float)vr[i], o[i]);
  }
  f16* dst = ao + (size_t)row * EE + h * 64 + sl * 8;
  #pragma unroll
  for (int i = 0; i < 8; ++i) dst[i] = (f16)o[i];
}

extern "C" void kernel_launch(void* const* d_in, const int* in_sizes, int n_in,
                              void* d_out, int out_size, void* d_ws, size_t ws_size,
                              hipStream_t stream) {
  const float* Q    = (const float*)d_in[0];
  const float* mk   = (const float*)d_in[1];
  const float* mv   = (const float*)d_in[2];
  const float* Wq   = (const float*)d_in[3];
  const float* bq   = (const float*)d_in[4];
  const float* Wk   = (const float*)d_in[5];
  const float* bk   = (const float*)d_in[6];
  const float* Wv   = (const float*)d_in[7];
  const float* bv   = (const float*)d_in[8];
  const float* Wiq  = (const float*)d_in[9];
  const float* Wik  = (const float*)d_in[10];
  const float* Wiv  = (const float*)d_in[11];
  const float* b_in = (const float*)d_in[12];
  const float* Wo   = (const float*)d_in[13];
  const float* bo   = (const float*)d_in[14];

  char* w = (char*)d_ws;
  size_t off = 0;
  auto alloc = [&](size_t bytes) { size_t o = off; off += (bytes + 255) & ~(size_t)255; return (void*)(w + o); };
  f16*    Kh     = (f16*)   alloc((size_t)NMEM * EE * 2);
  f16*    Qh     = (f16*)   alloc((size_t)BQ * EE * 2);   // dead after stage1 -> ao
  float*  sq32   = (float*) alloc((size_t)NMEM * 4);
  double* sq64   = (double*)alloc((size_t)NMEM * 8);
  f16*    Wc     = (f16*)   alloc((size_t)3 * EE * EE * 2);
  f16*    Wo16   = (f16*)   alloc((size_t)EE * EE * 2);
  float*  bc     = (float*) alloc((size_t)3 * EE * 4);
  int*    part_i = (int*)   alloc((size_t)BQ * NCAND * 4);
  float*  part_s = (float*) alloc((size_t)BQ * NCAND * 4);
  int*    idx5   = (int*)   alloc((size_t)BQ * 5 * 4);
  f16*    qp     = (f16*)   alloc((size_t)BQ * EE * 2);
  f16*    vp     = (f16*)   alloc((size_t)BQ * 5 * EE * 2);
  f16*    ao     = Qh;
  // big tier: separate kp + f16 value table -> gather projections read f16 (half traffic)
  size_t need_big = off + (size_t)NMEM * EE * 2 + (size_t)BQ * 5 * EE * 2 + 4096;
  bool big = (ws_size >= need_big);
  f16* Vh = nullptr;
  f16* kp;
  if (big) {
    Vh = (f16*)alloc((size_t)NMEM * EE * 2);
    kp = (f16*)alloc((size_t)BQ * 5 * EE * 2);
  } else {
    kp = Kh;   // overlay: Kh dead after stage1 in small tier
  }
  (void)in_sizes; (void)n_in; (void)out_size;

  k_prep_keys<<<NMEM / 4, 256, 0, stream>>>(mk, Kh, sq32, sq64);
  k_prep_f16<<<BQ / 4, 256, 0, stream>>>(Q, Qh);
  if (big) k_prep_f16<<<NMEM / 4, 256, 0, stream>>>(mv, Vh);
  k_compose<<<dim3(8, 8, 3), 256, 0, stream>>>(Wq, Wk, Wv, Wiq, Wik, Wiv, Wc);
  k_bias<<<3, 256, 0, stream>>>(Wiq, Wik, Wiv, bq, bk, bv, b_in, bc);
  k_cvtw<<<(EE * EE) / 256, 256, 0, stream>>>(Wo, Wo16);
  k_stage1<<<dim3(BQ / 256, NSEG), 512, 0, stream>>>(Qh, Kh, sq32, part_i, part_s);
  k_rescore<<<BQ, 64, 0, stream>>>(Q, mk, sq64, part_i, part_s, idx5);
  k_gemm<0><<<dim3(BQ / 64, 8), 256, 0, stream>>>(Qh, Wc, bc, qp);
  if (big) {
    k_gemm_g<1><<<dim3(BQ * 5 / 64, 8), 256, 0, stream>>>(idx5, Kh, Wc + (size_t)EE * EE, bc + EE, kp);
    k_gemm_g<1><<<dim3(BQ * 5 / 64, 8), 256, 0, stream>>>(idx5, Vh, Wc + (size_t)2 * EE * EE, bc + 2 * EE, vp);
  } else {
    k_gemm_g<0><<<dim3(BQ * 5 / 64, 8), 256, 0, stream>>>(idx5, mk, Wc + (size_t)EE * EE, bc + EE, kp);
    k_gemm_g<0><<<dim3(BQ * 5 / 64, 8), 256, 0, stream>>>(idx5, mv, Wc + (size_t)2 * EE * EE, bc + 2 * EE, vp);
  }
  k_attn<<<BQ / 4, 256, 0, stream>>>(qp, kp, vp, ao);
  k_gemm<1><<<dim3(BQ / 64, 8), 256, 0, stream>>>(ao, Wo16, bo, (float*)d_out);
}

// Round 8
// 920.074 us; speedup vs baseline: 2.3702x; 1.0496x over previous
//
#include <hip/hip_runtime.h>
#include <hip/hip_bf16.h>
#include <hip/hip_fp16.h>

typedef _Float16 f16;
typedef _Float16 f16x8 __attribute__((ext_vector_type(8)));
typedef float f32x4 __attribute__((ext_vector_type(4)));

constexpr int EE     = 512;
constexpr int NMEM   = 50000;
constexpr int BQ     = 8192;
constexpr int NSEG   = 16;
constexpr int SEGLEN = NMEM / NSEG;        // 3125 (exact)
constexpr int NT     = (SEGLEN + 15) / 16; // 196
constexpr int NC     = 6;                  // candidates kept per segment
constexpr int NCAND  = NSEG * NC;          // 96
constexpr int NRES   = 12;                 // exact-rescored candidates

// ---------------- prep: f32 -> fp16 keys + f64/f32 row norms ----------------
__global__ __launch_bounds__(256) void k_prep_keys(const float* __restrict__ mk,
                                                   f16* __restrict__ kh,
                                                   float* __restrict__ sq32,
                                                   double* __restrict__ sq64) {
  int row  = blockIdx.x * 4 + (threadIdx.x >> 6);
  int lane = threadIdx.x & 63;
  const float4* src = (const float4*)(mk + (size_t)row * EE) + lane * 2;
  float4 a = src[0], b = src[1];
  double s = (double)a.x*a.x + (double)a.y*a.y + (double)a.z*a.z + (double)a.w*a.w
           + (double)b.x*b.x + (double)b.y*b.y + (double)b.z*b.z + (double)b.w*b.w;
  f16x8 h;
  h[0]=(f16)a.x; h[1]=(f16)a.y; h[2]=(f16)a.z; h[3]=(f16)a.w;
  h[4]=(f16)b.x; h[5]=(f16)b.y; h[6]=(f16)b.z; h[7]=(f16)b.w;
  *((f16x8*)(kh + (size_t)row * EE) + lane) = h;
  #pragma unroll
  for (int o = 32; o > 0; o >>= 1) s += __shfl_down(s, o);
  if (lane == 0) { sq64[row] = s; sq32[row] = (float)s; }
}

// generic f32 -> f16 row copy (rows of EE)
__global__ __launch_bounds__(256) void k_prep_f16(const float* __restrict__ src,
                                                  f16* __restrict__ dst) {
  int row  = blockIdx.x * 4 + (threadIdx.x >> 6);
  int lane = threadIdx.x & 63;
  const float4* s = (const float4*)(src + (size_t)row * EE) + lane * 2;
  float4 a = s[0], b = s[1];
  f16x8 h;
  h[0]=(f16)a.x; h[1]=(f16)a.y; h[2]=(f16)a.z; h[3]=(f16)a.w;
  h[4]=(f16)b.x; h[5]=(f16)b.y; h[6]=(f16)b.z; h[7]=(f16)b.w;
  *((f16x8*)(dst + (size_t)row * EE) + lane) = h;
}

// ---------------- compose weights: Wc_m = Win_m @ W_m (f32 acc -> fp16 out) ----------------
__global__ __launch_bounds__(256) void k_compose(const float* __restrict__ Wq, const float* __restrict__ Wk,
                                                 const float* __restrict__ Wv, const float* __restrict__ Wiq,
                                                 const float* __restrict__ Wik, const float* __restrict__ Wiv,
                                                 f16* __restrict__ Wc) {
  int m = blockIdx.z;
  const float* A = (m == 0) ? Wiq : ((m == 1) ? Wik : Wiv);
  const float* B = (m == 0) ? Wq  : ((m == 1) ? Wk  : Wv);
  f16* C = Wc + (size_t)m * EE * EE;
  __shared__ float As[64][33];
  __shared__ float Bs[32][65];
  int i0 = blockIdx.x * 64, j0 = blockIdx.y * 64;
  int tx = threadIdx.x & 15, ty = threadIdx.x >> 4;
  float acc[4][4] = {};
  for (int kb = 0; kb < EE; kb += 32) {
    __syncthreads();
    #pragma unroll
    for (int v = 0; v < 8; ++v) {
      int idx = threadIdx.x + v * 256;
      As[idx >> 5][idx & 31] = A[(size_t)(i0 + (idx >> 5)) * EE + kb + (idx & 31)];
    }
    #pragma unroll
    for (int v = 0; v < 8; ++v) {
      int idx = threadIdx.x + v * 256;
      Bs[idx >> 6][idx & 63] = B[(size_t)(kb + (idx >> 6)) * EE + j0 + (idx & 63)];
    }
    __syncthreads();
    for (int t = 0; t < 32; ++t) {
      float av[4], bv[4];
      #pragma unroll
      for (int u = 0; u < 4; ++u) av[u] = As[ty*4+u][t];
      #pragma unroll
      for (int u = 0; u < 4; ++u) bv[u] = Bs[t][tx*4+u];
      #pragma unroll
      for (int a = 0; a < 4; ++a)
        #pragma unroll
        for (int b = 0; b < 4; ++b) acc[a][b] = fmaf(av[a], bv[b], acc[a][b]);
    }
  }
  #pragma unroll
  for (int a = 0; a < 4; ++a)
    #pragma unroll
    for (int b = 0; b < 4; ++b)
      C[(size_t)(i0 + ty*4 + a) * EE + j0 + tx*4 + b] = (f16)acc[a][b];
}

__global__ void k_bias(const float* __restrict__ Wiq, const float* __restrict__ Wik,
                       const float* __restrict__ Wiv, const float* __restrict__ bqv,
                       const float* __restrict__ bkv, const float* __restrict__ bvv,
                       const float* __restrict__ b_in, float* __restrict__ bc) {
  int m = blockIdx.x;
  const float* Wi = (m == 0) ? Wiq : ((m == 1) ? Wik : Wiv);
  const float* bb = (m == 0) ? bqv : ((m == 1) ? bkv : bvv);
  for (int i = threadIdx.x; i < EE; i += blockDim.x) {
    float s = 0.f;
    for (int t = 0; t < EE; ++t) s = fmaf(Wi[(size_t)i * EE + t], bb[t], s);
    bc[m * EE + i] = s + b_in[m * EE + i];
  }
}

__global__ void k_cvtw(const float* __restrict__ W, f16* __restrict__ Wo) {
  int i = blockIdx.x * 256 + threadIdx.x;
  Wo[i] = (f16)W[i];
}

// ---------------- stage 1: fp16 MFMA scores + per-segment top-6 ----------------
// 256 threads (4 waves x 32 rows), launch_bounds(256,2): fragments in arch VGPRs,
// 2 blocks/CU interleave barriers. Double-buffered Bt -> one barrier per tile.
// scratch2 as b128-written [4][16][9] f32x4 (slot-balanced, conflict-free scan reads).
__global__ __launch_bounds__(256, 2) void k_stage1(const f16* __restrict__ Qh,
                                                   const f16* __restrict__ Kh,
                                                   const float* __restrict__ sq32,
                                                   int* __restrict__ part_i,
                                                   float* __restrict__ part_s) {
  const int rb  = blockIdx.x;        // 0..63 (128 rows each)
  const int seg = blockIdx.y;        // 0..15
  const int tid = threadIdx.x;
  const int w   = tid >> 6;          // wave 0..3
  const int l   = tid & 63;
  const int lc  = l & 15, lp = l >> 4;
  const int seg_start = seg * SEGLEN;

  __shared__ f16   Bt[2][16 * 520];
  __shared__ float sqs[2][16];
  __shared__ f32x4 scratch2[4][16][9];   // [wave][key][qgroup(8) + pad]

  const int rowbase = rb * 128 + w * 32;
  f16x8 a0[16], a1[16];
  {
    const f16* base0 = Qh + (size_t)(rowbase + lc) * EE + lp * 8;
    const f16* base1 = base0 + (size_t)16 * EE;
    #pragma unroll
    for (int ks = 0; ks < 16; ++ks) {
      asm volatile("global_load_dwordx4 %0, %1, off"
                   : "=v"(a0[ks]) : "v"(base0 + ks * 32) : "memory");
      asm volatile("global_load_dwordx4 %0, %1, off"
                   : "=v"(a1[ks]) : "v"(base1 + ks * 32) : "memory");
    }
    asm volatile("s_waitcnt vmcnt(0)" ::: "memory");
    __builtin_amdgcn_sched_barrier(0);
  }

  float ts[NC]; int ti[NC];
  #pragma unroll
  for (int i = 0; i < NC; ++i) { ts[i] = -3.0e38f; ti[i] = 0; }
  const int hh = l >> 5;        // half of the 16 candidates this lane scans
  const int rr = l & 31;        // q-row within wave
  const int rg = rr >> 2, rq = rr & 3;

  float4 st0, st1, st2, st3; float stsq = 0.f;
  #define LOADT(tt) do { \
      int kk = seg_start + (tt) * 16; \
      int kb0 = kk + w * 4; \
      st0 = *(const float4*)(Kh + (size_t)(kb0 + 0) * EE + l * 8); \
      st1 = *(const float4*)(Kh + (size_t)(kb0 + 1) * EE + l * 8); \
      st2 = *(const float4*)(Kh + (size_t)(kb0 + 2) * EE + l * 8); \
      st3 = *(const float4*)(Kh + (size_t)(kb0 + 3) * EE + l * 8); \
      if (tid < 16) stsq = sq32[kk + tid]; \
    } while (0)
  #define STORET(buf) do { \
      *(float4*)&Bt[buf][(w*4 + 0) * 520 + l * 8] = st0; \
      *(float4*)&Bt[buf][(w*4 + 1) * 520 + l * 8] = st1; \
      *(float4*)&Bt[buf][(w*4 + 2) * 520 + l * 8] = st2; \
      *(float4*)&Bt[buf][(w*4 + 3) * 520 + l * 8] = st3; \
      if (tid < 16) sqs[buf][tid] = stsq; \
    } while (0)

  LOADT(0);
  STORET(0);
  for (int t = 0; t < NT; ++t) {
    const int c = t & 1;
    __syncthreads();               // buf[c] writes visible; buf[c^1] reads (t-1) done
    if (t + 1 < NT) LOADT(t + 1);  // global loads overlap compute

    f32x4 c0a = {0,0,0,0}, c0b = {0,0,0,0}, c1a = {0,0,0,0}, c1b = {0,0,0,0};
    #pragma unroll
    for (int ks = 0; ks < 8; ++ks) {
      f16x8 b0 = *(const f16x8*)&Bt[c][lc * 520 + ks * 32 + lp * 8];
      f16x8 b1 = *(const f16x8*)&Bt[c][lc * 520 + (ks + 8) * 32 + lp * 8];
      c0a = __builtin_amdgcn_mfma_f32_16x16x32_f16(a0[ks],     b0, c0a, 0, 0, 0);
      c1a = __builtin_amdgcn_mfma_f32_16x16x32_f16(a1[ks],     b0, c1a, 0, 0, 0);
      c0b = __builtin_amdgcn_mfma_f32_16x16x32_f16(a0[ks + 8], b1, c0b, 0, 0, 0);
      c1b = __builtin_amdgcn_mfma_f32_16x16x32_f16(a1[ks + 8], b1, c1b, 0, 0, 0);
    }
    f32x4 acc0 = c0a + c0b, acc1 = c1a + c1b;
    float myq = sqs[c][lc];
    scratch2[w][lc][lp]     = 2.0f * acc0 - myq;   // q-rows lp*4..+3, key lc
    scratch2[w][lc][lp + 4] = 2.0f * acc1 - myq;   // q-rows 16+lp*4..+3

    int nvalid = SEGLEN - t * 16; if (nvalid > 16) nvalid = 16;
    #pragma unroll
    for (int c8 = 0; c8 < 8; ++c8) {
      int ci = hh * 8 + c8;
      if (ci < nvalid) {
        float s = scratch2[w][ci][rg][rq];
        if (s > ts[NC-1]) {
          ts[NC-1] = s; ti[NC-1] = seg_start + t * 16 + ci;
          #pragma unroll
          for (int i = NC - 1; i > 0; --i) {
            if (ts[i] > ts[i-1]) {
              float tf = ts[i]; ts[i] = ts[i-1]; ts[i-1] = tf;
              int   tx = ti[i]; ti[i] = ti[i-1]; ti[i-1] = tx;
            }
          }
        }
      }
    }
    if (t + 1 < NT) STORET(c ^ 1);   // safe: (t-1)'s reads of buf[c^1] done at top barrier
  }
  #undef LOADT
  #undef STORET

  // merge lane pair (l, l^32)
  float ots[NC]; int oti[NC];
  #pragma unroll
  for (int i = 0; i < NC; ++i) {
    ots[i] = __shfl_xor(ts[i], 32);
    oti[i] = __shfl_xor(ti[i], 32);
  }
  if (l < 32) {
    #pragma unroll
    for (int j = 0; j < NC; ++j) {
      float s = ots[j]; int x = oti[j];
      if (s > ts[NC-1]) {
        ts[NC-1] = s; ti[NC-1] = x;
        #pragma unroll
        for (int i = NC - 1; i > 0; --i) {
          if (ts[i] > ts[i-1]) {
            float tf = ts[i]; ts[i] = ts[i-1]; ts[i-1] = tf;
            int   tx = ti[i]; ti[i] = ti[i-1]; ti[i-1] = tx;
          }
        }
      }
    }
    int row = rowbase + l;
    #pragma unroll
    for (int i = 0; i < NC; ++i) {
      part_i[(size_t)row * NCAND + seg * NC + i] = ti[i];
      part_s[(size_t)row * NCAND + seg * NC + i] = ts[i];
    }
  }
}

// ---------------- stage 2: noisy top-12 of 96, exact f64 rescore -> top-5 ----------------
__global__ __launch_bounds__(64) void k_rescore(const float* __restrict__ Q,
                                                const float* __restrict__ mk,
                                                const double* __restrict__ sq64,
                                                const int* __restrict__ part_i,
                                                const float* __restrict__ part_s,
                                                int* __restrict__ idx5) {
  const int row = blockIdx.x;
  const int l = threadIdx.x;
  const float* Qr = Q + (size_t)row * EE;
  float q[8];
  #pragma unroll
  for (int i = 0; i < 8; ++i) q[i] = Qr[l + 64*i];
  // lane l holds candidate l; lanes 0..31 also hold candidate 64+l
  float s0 = part_s[(size_t)row * NCAND + l];
  int   i0 = part_i[(size_t)row * NCAND + l];
  float s1 = (l < 32) ? part_s[(size_t)row * NCAND + 64 + l] : -3.0e38f;
  int   i1 = (l < 32) ? part_i[(size_t)row * NCAND + 64 + l] : 0;

  double bs[5] = {-1e300, -1e300, -1e300, -1e300, -1e300};
  int    bi[5] = {0, 0, 0, 0, 0};
  #pragma unroll
  for (int p = 0; p < NRES; ++p) {
    bool pick0 = (s0 >= s1);
    float m  = pick0 ? s0 : s1;
    int   mi = pick0 ? i0 : i1;
    int   code = (l << 1) | (pick0 ? 0 : 1);
    #pragma unroll
    for (int o = 32; o > 0; o >>= 1) {
      float mo = __shfl_xor(m, o);
      int   io = __shfl_xor(mi, o);
      int   co = __shfl_xor(code, o);
      if (mo > m || (mo == m && co < code)) { m = mo; mi = io; code = co; }
    }
    if ((code >> 1) == l) { if (code & 1) s1 = -3.0e38f; else s0 = -3.0e38f; }
    const float* kr = mk + (size_t)mi * EE;
    double pd = 0.0;
    #pragma unroll
    for (int i = 0; i < 8; ++i) pd += (double)q[i] * (double)kr[l + 64*i];
    #pragma unroll
    for (int o = 32; o > 0; o >>= 1) pd += __shfl_down(pd, o);
    if (l == 0) {
      double s = 2.0 * pd - sq64[mi];
      if (s > bs[4]) {
        bs[4] = s; bi[4] = mi;
        #pragma unroll
        for (int i = 4; i > 0; --i) {
          if (bs[i] > bs[i-1]) {
            double tf = bs[i]; bs[i] = bs[i-1]; bs[i-1] = tf;
            int    tx = bi[i]; bi[i] = bi[i-1]; bi[i-1] = tx;
          }
        }
      }
    }
  }
  if (l == 0) {
    #pragma unroll
    for (int i = 0; i < 5; ++i) idx5[(size_t)row*5 + i] = bi[i];
  }
}

// ---------------- fp16 MFMA GEMM: C = A @ B^T + bias (64x64 tile) ----------------
template <int OUTF32>
__global__ __launch_bounds__(256) void k_gemm(const f16* __restrict__ A, const f16* __restrict__ B,
                                              const float* __restrict__ bias, void* __restrict__ outp) {
  __shared__ f16 As[64][72];
  __shared__ f16 Bs[64][72];
  const int tid = threadIdx.x;
  const int wv = tid >> 6, l = tid & 63, lc = l & 15, lp = l >> 4;
  const int m0 = blockIdx.x * 64, n0 = blockIdx.y * 64;
  const int r = tid >> 2, co = (tid & 3) * 16;
  f32x4 acc[4] = {{0,0,0,0},{0,0,0,0},{0,0,0,0},{0,0,0,0}};
  for (int kb = 0; kb < EE; kb += 64) {
    __syncthreads();
    *(float4*)&As[r][co]     = *(const float4*)(A + (size_t)(m0 + r) * EE + kb + co);
    *(float4*)&As[r][co + 8] = *(const float4*)(A + (size_t)(m0 + r) * EE + kb + co + 8);
    *(float4*)&Bs[r][co]     = *(const float4*)(B + (size_t)(n0 + r) * EE + kb + co);
    *(float4*)&Bs[r][co + 8] = *(const float4*)(B + (size_t)(n0 + r) * EE + kb + co + 8);
    __syncthreads();
    #pragma unroll
    for (int ks = 0; ks < 2; ++ks) {
      f16x8 a = *(const f16x8*)&As[wv*16 + lc][ks*32 + lp*8];
      #pragma unroll
      for (int f = 0; f < 4; ++f) {
        f16x8 b = *(const f16x8*)&Bs[f*16 + lc][ks*32 + lp*8];
        acc[f] = __builtin_amdgcn_mfma_f32_16x16x32_f16(a, b, acc[f], 0, 0, 0);
      }
    }
  }
  #pragma unroll
  for (int f = 0; f < 4; ++f) {
    int col = n0 + f*16 + lc;
    float bsv = bias[col];
    #pragma unroll
    for (int rr = 0; rr < 4; ++rr) {
      int row = m0 + wv*16 + lp*4 + rr;
      float v = acc[f][rr] + bsv;
      if (OUTF32) ((float*)outp)[(size_t)row * EE + col] = v;
      else        ((f16*)outp)[(size_t)row * EE + col] = (f16)v;
    }
  }
}

// gather variant: A rows from mem[idx[row]]; AF16: A already f16, else f32 -> f16 inline
template <int AF16>
__global__ __launch_bounds__(256) void k_gemm_g(const int* __restrict__ gidx, const void* __restrict__ Asrc,
                                                const f16* __restrict__ B, const float* __restrict__ bias,
                                                f16* __restrict__ outp) {
  __shared__ f16 As[64][72];
  __shared__ f16 Bs[64][72];
  const int tid = threadIdx.x;
  const int wv = tid >> 6, l = tid & 63, lc = l & 15, lp = l >> 4;
  const int m0 = blockIdx.x * 64, n0 = blockIdx.y * 64;
  const int r = tid >> 2, co = (tid & 3) * 16;
  const int gi = gidx[m0 + r];
  f32x4 acc[4] = {{0,0,0,0},{0,0,0,0},{0,0,0,0},{0,0,0,0}};
  for (int kb = 0; kb < EE; kb += 64) {
    __syncthreads();
    if (AF16) {
      const f16* arow = (const f16*)Asrc + (size_t)gi * EE;
      *(f16x8*)&As[r][co]     = *(const f16x8*)(arow + kb + co);
      *(f16x8*)&As[r][co + 8] = *(const f16x8*)(arow + kb + co + 8);
    } else {
      const float* arow = (const float*)Asrc + (size_t)gi * EE;
      float4 x0 = *(const float4*)(arow + kb + co);
      float4 x1 = *(const float4*)(arow + kb + co + 4);
      float4 x2 = *(const float4*)(arow + kb + co + 8);
      float4 x3 = *(const float4*)(arow + kb + co + 12);
      f16x8 h0, h1;
      h0[0]=(f16)x0.x; h0[1]=(f16)x0.y; h0[2]=(f16)x0.z; h0[3]=(f16)x0.w;
      h0[4]=(f16)x1.x; h0[5]=(f16)x1.y; h0[6]=(f16)x1.z; h0[7]=(f16)x1.w;
      h1[0]=(f16)x2.x; h1[1]=(f16)x2.y; h1[2]=(f16)x2.z; h1[3]=(f16)x2.w;
      h1[4]=(f16)x3.x; h1[5]=(f16)x3.y; h1[6]=(f16)x3.z; h1[7]=(f16)x3.w;
      *(f16x8*)&As[r][co]     = h0;
      *(f16x8*)&As[r][co + 8] = h1;
    }
    *(float4*)&Bs[r][co]     = *(const float4*)(B + (size_t)(n0 + r) * EE + kb + co);
    *(float4*)&Bs[r][co + 8] = *(const float4*)(B + (size_t)(n0 + r) * EE + kb + co + 8);
    __syncthreads();
    #pragma unroll
    for (int ks = 0; ks < 2; ++ks) {
      f16x8 a = *(const f16x8*)&As[wv*16 + lc][ks*32 + lp*8];
      #pragma unroll
      for (int f = 0; f < 4; ++f) {
        f16x8 b = *(const f16x8*)&Bs[f*16 + lc][ks*32 + lp*8];
        acc[f] = __builtin_amdgcn_mfma_f32_16x16x32_f16(a, b, acc[f], 0, 0, 0);
      }
    }
  }
  #pragma unroll
  for (int f = 0; f < 4; ++f) {
    int col = n0 + f*16 + lc;
    float bsv = bias[col];
    #pragma unroll
    for (int rr = 0; rr < 4; ++rr) {
      int row = m0 + wv*16 + lp*4 + rr;
      outp[(size_t)row * EE + col] = (f16)(acc[f][rr] + bsv);
    }
  }
}

// ---------------- 5-key MHA (H=8, d=64), f32 compute ----------------
__global__ __launch_bounds__(256) void k_attn(const f16* __restrict__ qp, const f16* __restrict__ kp,
                                              const f16* __restrict__ vp, f16* __restrict__ ao) {
  int row = blockIdx.x * 4 + (threadIdx.x >> 6);
  int l = threadIdx.x & 63;
  int h = l >> 3, sl = l & 7;
  const f16* q = qp + (size_t)row * EE + h * 64 + sl * 8;
  float qv[8];
  #pragma unroll
  for (int i = 0; i < 8; ++i) qv[i] = (float)q[i];
  float sc[5];
  #pragma unroll
  for (int j = 0; j < 5; ++j) {
    const f16* kr = kp + ((size_t)row * 5 + j) * EE + h * 64 + sl * 8;
    float p = 0.f;
    #pragma unroll
    for (int i = 0; i < 8; ++i) p = fmaf(qv[i], (float)kr[i], p);
    p += __shfl_xor(p, 1); p += __shfl_xor(p, 2); p += __shfl_xor(p, 4);
    sc[j] = p * 0.125f;
  }
  float mx = fmaxf(fmaxf(fmaxf(sc[0], sc[1]), fmaxf(sc[2], sc[3])), sc[4]);
  float sum = 0.f;
  #pragma unroll
  for (int j = 0; j < 5; ++j) { sc[j] = __expf(sc[j] - mx); sum += sc[j]; }
  float inv = 1.0f / sum;
  float o[8] = {};
  #pragma unroll
  for (int j = 0; j < 5; ++j) {
    const f16* vr = vp + ((size_t)row * 5 + j) * EE + h * 64 + sl * 8;
    float aw = sc[j] * inv;
    #pragma unroll
    for (int i = 0; i < 8; ++i) o[i] = fmaf(aw, (float)vr[i], o[i]);
  }
  f16* dst = ao + (size_t)row * EE + h * 64 + sl * 8;
  #pragma unroll
  for (int i = 0; i < 8; ++i) dst[i] = (f16)o[i];
}

extern "C" void kernel_launch(void* const* d_in, const int* in_sizes, int n_in,
                              void* d_out, int out_size, void* d_ws, size_t ws_size,
                              hipStream_t stream) {
  const float* Q    = (const float*)d_in[0];
  const float* mk   = (const float*)d_in[1];
  const float* mv   = (const float*)d_in[2];
  const float* Wq   = (const float*)d_in[3];
  const float* bq   = (const float*)d_in[4];
  const float* Wk   = (const float*)d_in[5];
  const float* bk   = (const float*)d_in[6];
  const float* Wv   = (const float*)d_in[7];
  const float* bv   = (const float*)d_in[8];
  const float* Wiq  = (const float*)d_in[9];
  const float* Wik  = (const float*)d_in[10];
  const float* Wiv  = (const float*)d_in[11];
  const float* b_in = (const float*)d_in[12];
  const float* Wo   = (const float*)d_in[13];
  const float* bo   = (const float*)d_in[14];

  char* w = (char*)d_ws;
  size_t off = 0;
  auto alloc = [&](size_t bytes) { size_t o = off; off += (bytes + 255) & ~(size_t)255; return (void*)(w + o); };
  f16*    Kh     = (f16*)   alloc((size_t)NMEM * EE * 2);
  f16*    Qh     = (f16*)   alloc((size_t)BQ * EE * 2);   // dead after stage1 -> ao
  float*  sq32   = (float*) alloc((size_t)NMEM * 4);
  double* sq64   = (double*)alloc((size_t)NMEM * 8);
  f16*    Wc     = (f16*)   alloc((size_t)3 * EE * EE * 2);
  f16*    Wo16   = (f16*)   alloc((size_t)EE * EE * 2);
  float*  bc     = (float*) alloc((size_t)3 * EE * 4);
  int*    part_i = (int*)   alloc((size_t)BQ * NCAND * 4);
  float*  part_s = (float*) alloc((size_t)BQ * NCAND * 4);
  int*    idx5   = (int*)   alloc((size_t)BQ * 5 * 4);
  f16*    qp     = (f16*)   alloc((size_t)BQ * EE * 2);
  f16*    vp     = (f16*)   alloc((size_t)BQ * 5 * EE * 2);
  f16*    ao     = Qh;
  // big tier: separate kp + f16 value table -> gather projections read f16 (half traffic)
  size_t need_big = off + (size_t)NMEM * EE * 2 + (size_t)BQ * 5 * EE * 2 + 4096;
  bool big = (ws_size >= need_big);
  f16* Vh = nullptr;
  f16* kp;
  if (big) {
    Vh = (f16*)alloc((size_t)NMEM * EE * 2);
    kp = (f16*)alloc((size_t)BQ * 5 * EE * 2);
  } else {
    kp = Kh;   // overlay: Kh dead after stage1 in small tier
  }
  (void)in_sizes; (void)n_in; (void)out_size;

  k_prep_keys<<<NMEM / 4, 256, 0, stream>>>(mk, Kh, sq32, sq64);
  k_prep_f16<<<BQ / 4, 256, 0, stream>>>(Q, Qh);
  if (big) k_prep_f16<<<NMEM / 4, 256, 0, stream>>>(mv, Vh);
  k_compose<<<dim3(8, 8, 3), 256, 0, stream>>>(Wq, Wk, Wv, Wiq, Wik, Wiv, Wc);
  k_bias<<<3, 256, 0, stream>>>(Wiq, Wik, Wiv, bq, bk, bv, b_in, bc);
  k_cvtw<<<(EE * EE) / 256, 256, 0, stream>>>(Wo, Wo16);
  k_stage1<<<dim3(BQ / 128, NSEG), 256, 0, stream>>>(Qh, Kh, sq32, part_i, part_s);
  k_rescore<<<BQ, 64, 0, stream>>>(Q, mk, sq64, part_i, part_s, idx5);
  k_gemm<0><<<dim3(BQ / 64, 8), 256, 0, stream>>>(Qh, Wc, bc, qp);
  if (big) {
    k_gemm_g<1><<<dim3(BQ * 5 / 64, 8), 256, 0, stream>>>(idx5, Kh, Wc + (size_t)EE * EE, bc + EE, kp);
    k_gemm_g<1><<<dim3(BQ * 5 / 64, 8), 256, 0, stream>>>(idx5, Vh, Wc + (size_t)2 * EE * EE, bc + 2 * EE, vp);
  } else {
    k_gemm_g<0><<<dim3(BQ * 5 / 64, 8), 256, 0, stream>>>(idx5, mk, Wc + (size_t)EE * EE, bc + EE, kp);
    k_gemm_g<0><<<dim3(BQ * 5 / 64, 8), 256, 0, stream>>>(idx5, mv, Wc + (size_t)2 * EE * EE, bc + 2 * EE, vp);
  }
  k_attn<<<BQ / 4, 256, 0, stream>>>(qp, kp, vp, ao);
  k_gemm<1><<<dim3(BQ / 64, 8), 256, 0, stream>>>(ao, Wo16, bo, (float*)d_out);
}

// Round 9
// 861.630 us; speedup vs baseline: 2.5309x; 1.0678x over previous
//
#include <hip/hip_runtime.h>
#include <hip/hip_bf16.h>
#include <hip/hip_fp16.h>

typedef _Float16 f16;
typedef _Float16 f16x8 __attribute__((ext_vector_type(8)));
typedef float f32x4 __attribute__((ext_vector_type(4)));

constexpr int EE     = 512;
constexpr int NMEM   = 50000;
constexpr int BQ     = 8192;
constexpr int NSEG   = 16;
constexpr int SEGLEN = NMEM / NSEG;            // 3125 (exact)
constexpr int KVT    = 32;                     // keys per tile
constexpr int NT32   = (SEGLEN + KVT - 1) / KVT; // 98
constexpr int NC     = 6;                      // candidates kept per segment
constexpr int NCAND  = NSEG * NC;              // 96
constexpr int NRES   = 12;                     // exact-rescored candidates

// ---------------- prep: f32 -> fp16 keys + f64/f32 row norms ----------------
__global__ __launch_bounds__(256) void k_prep_keys(const float* __restrict__ mk,
                                                   f16* __restrict__ kh,
                                                   float* __restrict__ sq32,
                                                   double* __restrict__ sq64) {
  int row  = blockIdx.x * 4 + (threadIdx.x >> 6);
  int lane = threadIdx.x & 63;
  const float4* src = (const float4*)(mk + (size_t)row * EE) + lane * 2;
  float4 a = src[0], b = src[1];
  double s = (double)a.x*a.x + (double)a.y*a.y + (double)a.z*a.z + (double)a.w*a.w
           + (double)b.x*b.x + (double)b.y*b.y + (double)b.z*b.z + (double)b.w*b.w;
  f16x8 h;
  h[0]=(f16)a.x; h[1]=(f16)a.y; h[2]=(f16)a.z; h[3]=(f16)a.w;
  h[4]=(f16)b.x; h[5]=(f16)b.y; h[6]=(f16)b.z; h[7]=(f16)b.w;
  *((f16x8*)(kh + (size_t)row * EE) + lane) = h;
  #pragma unroll
  for (int o = 32; o > 0; o >>= 1) s += __shfl_down(s, o);
  if (lane == 0) { sq64[row] = s; sq32[row] = (float)s; }
}

// generic f32 -> f16 row copy (rows of EE)
__global__ __launch_bounds__(256) void k_prep_f16(const float* __restrict__ src,
                                                  f16* __restrict__ dst) {
  int row  = blockIdx.x * 4 + (threadIdx.x >> 6);
  int lane = threadIdx.x & 63;
  const float4* s = (const float4*)(src + (size_t)row * EE) + lane * 2;
  float4 a = s[0], b = s[1];
  f16x8 h;
  h[0]=(f16)a.x; h[1]=(f16)a.y; h[2]=(f16)a.z; h[3]=(f16)a.w;
  h[4]=(f16)b.x; h[5]=(f16)b.y; h[6]=(f16)b.z; h[7]=(f16)b.w;
  *((f16x8*)(dst + (size_t)row * EE) + lane) = h;
}

// ---------------- compose weights: Wc_m = Win_m @ W_m (f32 acc -> fp16 out) ----------------
__global__ __launch_bounds__(256) void k_compose(const float* __restrict__ Wq, const float* __restrict__ Wk,
                                                 const float* __restrict__ Wv, const float* __restrict__ Wiq,
                                                 const float* __restrict__ Wik, const float* __restrict__ Wiv,
                                                 f16* __restrict__ Wc) {
  int m = blockIdx.z;
  const float* A = (m == 0) ? Wiq : ((m == 1) ? Wik : Wiv);
  const float* B = (m == 0) ? Wq  : ((m == 1) ? Wk  : Wv);
  f16* C = Wc + (size_t)m * EE * EE;
  __shared__ float As[64][33];
  __shared__ float Bs[32][65];
  int i0 = blockIdx.x * 64, j0 = blockIdx.y * 64;
  int tx = threadIdx.x & 15, ty = threadIdx.x >> 4;
  float acc[4][4] = {};
  for (int kb = 0; kb < EE; kb += 32) {
    __syncthreads();
    #pragma unroll
    for (int v = 0; v < 8; ++v) {
      int idx = threadIdx.x + v * 256;
      As[idx >> 5][idx & 31] = A[(size_t)(i0 + (idx >> 5)) * EE + kb + (idx & 31)];
    }
    #pragma unroll
    for (int v = 0; v < 8; ++v) {
      int idx = threadIdx.x + v * 256;
      Bs[idx >> 6][idx & 63] = B[(size_t)(kb + (idx >> 6)) * EE + j0 + (idx & 63)];
    }
    __syncthreads();
    for (int t = 0; t < 32; ++t) {
      float av[4], bv[4];
      #pragma unroll
      for (int u = 0; u < 4; ++u) av[u] = As[ty*4+u][t];
      #pragma unroll
      for (int u = 0; u < 4; ++u) bv[u] = Bs[t][tx*4+u];
      #pragma unroll
      for (int a = 0; a < 4; ++a)
        #pragma unroll
        for (int b = 0; b < 4; ++b) acc[a][b] = fmaf(av[a], bv[b], acc[a][b]);
    }
  }
  #pragma unroll
  for (int a = 0; a < 4; ++a)
    #pragma unroll
    for (int b = 0; b < 4; ++b)
      C[(size_t)(i0 + ty*4 + a) * EE + j0 + tx*4 + b] = (f16)acc[a][b];
}

__global__ void k_bias(const float* __restrict__ Wiq, const float* __restrict__ Wik,
                       const float* __restrict__ Wiv, const float* __restrict__ bqv,
                       const float* __restrict__ bkv, const float* __restrict__ bvv,
                       const float* __restrict__ b_in, float* __restrict__ bc) {
  int m = blockIdx.x;
  const float* Wi = (m == 0) ? Wiq : ((m == 1) ? Wik : Wiv);
  const float* bb = (m == 0) ? bqv : ((m == 1) ? bkv : bvv);
  for (int i = threadIdx.x; i < EE; i += blockDim.x) {
    float s = 0.f;
    for (int t = 0; t < EE; ++t) s = fmaf(Wi[(size_t)i * EE + t], bb[t], s);
    bc[m * EE + i] = s + b_in[m * EE + i];
  }
}

__global__ void k_cvtw(const float* __restrict__ W, f16* __restrict__ Wo) {
  int i = blockIdx.x * 256 + threadIdx.x;
  Wo[i] = (f16)W[i];
}

// ---------------- stage 1: swapped-operand fp16 MFMA scores, register top-6 ----------------
// mfma(K_frag, Q_frag): D[key][qrow]; lane holds qrow = lane&15, keys (lane>>4)*4+reg.
// Selection is per-lane register inserts (key-striped), merged via shfl_xor at the end.
__global__ __launch_bounds__(256, 2) void k_stage1(const f16* __restrict__ Qh,
                                                   const f16* __restrict__ Kh,
                                                   const float* __restrict__ sq32,
                                                   int* __restrict__ part_i,
                                                   float* __restrict__ part_s) {
  const int rb  = blockIdx.x;        // 0..63 (128 rows each)
  const int seg = blockIdx.y;        // 0..15
  const int tid = threadIdx.x;
  const int w   = tid >> 6;          // wave 0..3
  const int l   = tid & 63;
  const int lc  = l & 15, lp = l >> 4;
  const int seg_start = seg * SEGLEN;
  const int seg_end   = seg_start + SEGLEN;

  __shared__ f16   Bt[2][KVT * 520];
  __shared__ float sqs[2][KVT];

  const int rowbase = rb * 128 + w * 32;
  f16x8 a0[16], a1[16];
  {
    const f16* base0 = Qh + (size_t)(rowbase + lc) * EE + lp * 8;
    const f16* base1 = base0 + (size_t)16 * EE;
    #pragma unroll
    for (int ks = 0; ks < 16; ++ks) {
      asm volatile("global_load_dwordx4 %0, %1, off"
                   : "=v"(a0[ks]) : "v"(base0 + ks * 32) : "memory");
      asm volatile("global_load_dwordx4 %0, %1, off"
                   : "=v"(a1[ks]) : "v"(base1 + ks * 32) : "memory");
    }
    asm volatile("s_waitcnt vmcnt(0)" ::: "memory");
    __builtin_amdgcn_sched_barrier(0);
  }

  // ts0/ti0: q-row (rowbase+lc); ts1/ti1: q-row (rowbase+16+lc). Key-striped by lp.
  float ts0[NC], ts1[NC]; int ti0[NC], ti1[NC];
  #pragma unroll
  for (int i = 0; i < NC; ++i) {
    ts0[i] = -3.0e38f; ti0[i] = 0;
    ts1[i] = -3.0e38f; ti1[i] = 0;
  }

#define INS(TS, TI, SV, IV) do { \
    if ((SV) > TS[NC-1]) { \
      TS[NC-1] = (SV); TI[NC-1] = (IV); \
      _Pragma("unroll") \
      for (int _i = NC - 1; _i > 0; --_i) { \
        if (TS[_i] > TS[_i-1]) { \
          float _tf = TS[_i]; TS[_i] = TS[_i-1]; TS[_i-1] = _tf; \
          int   _tx = TI[_i]; TI[_i] = TI[_i-1]; TI[_i-1] = _tx; \
        } \
      } \
    } \
  } while (0)

  float4 st[8]; float stsq = 0.f;
  #define LOADT(tt) do { \
      int kk = seg_start + (tt) * KVT; \
      _Pragma("unroll") \
      for (int j = 0; j < 8; ++j) { \
        int key = kk + w * 8 + j; \
        key = key < NMEM ? key : NMEM - 1; \
        st[j] = *(const float4*)(Kh + (size_t)key * EE + l * 8); \
      } \
      if (tid < KVT) { int kq = kk + tid; stsq = sq32[kq < NMEM ? kq : NMEM - 1]; } \
    } while (0)
  #define STORET(buf) do { \
      _Pragma("unroll") \
      for (int j = 0; j < 8; ++j) \
        *(float4*)&Bt[buf][(w*8 + j) * 520 + l * 8] = st[j]; \
      if (tid < KVT) sqs[buf][tid] = stsq; \
    } while (0)

  LOADT(0);
  STORET(0);
  for (int t = 0; t < NT32; ++t) {
    const int c = t & 1;
    __syncthreads();               // buf[c] visible; prev reads of buf[c^1] done
    if (t + 1 < NT32) LOADT(t + 1);

    f32x4 A00 = {0,0,0,0}, A01 = {0,0,0,0}, A10 = {0,0,0,0}, A11 = {0,0,0,0};
    #pragma unroll
    for (int ks = 0; ks < 16; ++ks) {
      f16x8 kf0 = *(const f16x8*)&Bt[c][lc * 520 + ks * 32 + lp * 8];
      f16x8 kf1 = *(const f16x8*)&Bt[c][(16 + lc) * 520 + ks * 32 + lp * 8];
      A00 = __builtin_amdgcn_mfma_f32_16x16x32_f16(kf0, a0[ks], A00, 0, 0, 0);
      A01 = __builtin_amdgcn_mfma_f32_16x16x32_f16(kf0, a1[ks], A01, 0, 0, 0);
      A10 = __builtin_amdgcn_mfma_f32_16x16x32_f16(kf1, a0[ks], A10, 0, 0, 0);
      A11 = __builtin_amdgcn_mfma_f32_16x16x32_f16(kf1, a1[ks], A11, 0, 0, 0);
    }
    // epilogue: per-lane scores, register inserts
    float4 q0 = *(const float4*)&sqs[c][lp * 4];        // keys kb + lp*4 + r
    float4 q1 = *(const float4*)&sqs[c][16 + lp * 4];   // keys kb + 16 + lp*4 + r
    const int kb = seg_start + t * KVT;
    #pragma unroll
    for (int r = 0; r < 4; ++r) {
      float qv0 = (r == 0) ? q0.x : (r == 1) ? q0.y : (r == 2) ? q0.z : q0.w;
      float qv1 = (r == 0) ? q1.x : (r == 1) ? q1.y : (r == 2) ? q1.z : q1.w;
      int i0v = kb + lp * 4 + r;
      int i1v = kb + 16 + lp * 4 + r;
      float s00 = (i0v < seg_end) ? 2.0f * A00[r] - qv0 : -3.0e38f;  // rows 0-15, keys 0-15
      float s01 = (i0v < seg_end) ? 2.0f * A01[r] - qv0 : -3.0e38f;  // rows 16-31, keys 0-15
      float s10 = (i1v < seg_end) ? 2.0f * A10[r] - qv1 : -3.0e38f;  // rows 0-15, keys 16-31
      float s11 = (i1v < seg_end) ? 2.0f * A11[r] - qv1 : -3.0e38f;  // rows 16-31, keys 16-31
      INS(ts0, ti0, s00, i0v);
      INS(ts0, ti0, s10, i1v);
      INS(ts1, ti1, s01, i0v);
      INS(ts1, ti1, s11, i1v);
    }
    if (t + 1 < NT32) STORET(c ^ 1);
  }
  #undef LOADT
  #undef STORET

  // merge key-stripes: lanes {lc, lc+16, lc+32, lc+48} hold disjoint stripes of same q-rows
  #pragma unroll
  for (int d = 16; d <= 32; d <<= 1) {
    float os[NC]; int oi[NC];
    #pragma unroll
    for (int i = 0; i < NC; ++i) { os[i] = __shfl_xor(ts0[i], d); oi[i] = __shfl_xor(ti0[i], d); }
    #pragma unroll
    for (int j = 0; j < NC; ++j) INS(ts0, ti0, os[j], oi[j]);
    #pragma unroll
    for (int i = 0; i < NC; ++i) { os[i] = __shfl_xor(ts1[i], d); oi[i] = __shfl_xor(ti1[i], d); }
    #pragma unroll
    for (int j = 0; j < NC; ++j) INS(ts1, ti1, os[j], oi[j]);
  }
#undef INS
  if (l < 16) {
    int row = rowbase + lc;
    #pragma unroll
    for (int i = 0; i < NC; ++i) {
      part_i[(size_t)row * NCAND + seg * NC + i] = ti0[i];
      part_s[(size_t)row * NCAND + seg * NC + i] = ts0[i];
    }
  } else if (l < 32) {
    int row = rowbase + 16 + lc;
    #pragma unroll
    for (int i = 0; i < NC; ++i) {
      part_i[(size_t)row * NCAND + seg * NC + i] = ti1[i];
      part_s[(size_t)row * NCAND + seg * NC + i] = ts1[i];
    }
  }
}

// ---------------- stage 2: noisy top-12 of 96, exact f64 rescore -> top-5 ----------------
__global__ __launch_bounds__(64) void k_rescore(const float* __restrict__ Q,
                                                const float* __restrict__ mk,
                                                const double* __restrict__ sq64,
                                                const int* __restrict__ part_i,
                                                const float* __restrict__ part_s,
                                                int* __restrict__ idx5) {
  const int row = blockIdx.x;
  const int l = threadIdx.x;
  const float* Qr = Q + (size_t)row * EE;
  float q[8];
  #pragma unroll
  for (int i = 0; i < 8; ++i) q[i] = Qr[l + 64*i];
  float s0 = part_s[(size_t)row * NCAND + l];
  int   i0 = part_i[(size_t)row * NCAND + l];
  float s1 = (l < 32) ? part_s[(size_t)row * NCAND + 64 + l] : -3.0e38f;
  int   i1 = (l < 32) ? part_i[(size_t)row * NCAND + 64 + l] : 0;

  double bs[5] = {-1e300, -1e300, -1e300, -1e300, -1e300};
  int    bi[5] = {0, 0, 0, 0, 0};
  #pragma unroll
  for (int p = 0; p < NRES; ++p) {
    bool pick0 = (s0 >= s1);
    float m  = pick0 ? s0 : s1;
    int   mi = pick0 ? i0 : i1;
    int   code = (l << 1) | (pick0 ? 0 : 1);
    #pragma unroll
    for (int o = 32; o > 0; o >>= 1) {
      float mo = __shfl_xor(m, o);
      int   io = __shfl_xor(mi, o);
      int   co = __shfl_xor(code, o);
      if (mo > m || (mo == m && co < code)) { m = mo; mi = io; code = co; }
    }
    if ((code >> 1) == l) { if (code & 1) s1 = -3.0e38f; else s0 = -3.0e38f; }
    const float* kr = mk + (size_t)mi * EE;
    double pd = 0.0;
    #pragma unroll
    for (int i = 0; i < 8; ++i) pd += (double)q[i] * (double)kr[l + 64*i];
    #pragma unroll
    for (int o = 32; o > 0; o >>= 1) pd += __shfl_down(pd, o);
    if (l == 0) {
      double s = 2.0 * pd - sq64[mi];
      if (s > bs[4]) {
        bs[4] = s; bi[4] = mi;
        #pragma unroll
        for (int i = 4; i > 0; --i) {
          if (bs[i] > bs[i-1]) {
            double tf = bs[i]; bs[i] = bs[i-1]; bs[i-1] = tf;
            int    tx = bi[i]; bi[i] = bi[i-1]; bi[i-1] = tx;
          }
        }
      }
    }
  }
  if (l == 0) {
    #pragma unroll
    for (int i = 0; i < 5; ++i) idx5[(size_t)row*5 + i] = bi[i];
  }
}

// ---------------- fp16 MFMA GEMM: C = A @ B^T + bias (64x64 tile) ----------------
template <int OUTF32>
__global__ __launch_bounds__(256) void k_gemm(const f16* __restrict__ A, const f16* __restrict__ B,
                                              const float* __restrict__ bias, void* __restrict__ outp) {
  __shared__ f16 As[64][72];
  __shared__ f16 Bs[64][72];
  const int tid = threadIdx.x;
  const int wv = tid >> 6, l = tid & 63, lc = l & 15, lp = l >> 4;
  const int m0 = blockIdx.x * 64, n0 = blockIdx.y * 64;
  const int r = tid >> 2, co = (tid & 3) * 16;
  f32x4 acc[4] = {{0,0,0,0},{0,0,0,0},{0,0,0,0},{0,0,0,0}};
  for (int kb = 0; kb < EE; kb += 64) {
    __syncthreads();
    *(float4*)&As[r][co]     = *(const float4*)(A + (size_t)(m0 + r) * EE + kb + co);
    *(float4*)&As[r][co + 8] = *(const float4*)(A + (size_t)(m0 + r) * EE + kb + co + 8);
    *(float4*)&Bs[r][co]     = *(const float4*)(B + (size_t)(n0 + r) * EE + kb + co);
    *(float4*)&Bs[r][co + 8] = *(const float4*)(B + (size_t)(n0 + r) * EE + kb + co + 8);
    __syncthreads();
    #pragma unroll
    for (int ks = 0; ks < 2; ++ks) {
      f16x8 a = *(const f16x8*)&As[wv*16 + lc][ks*32 + lp*8];
      #pragma unroll
      for (int f = 0; f < 4; ++f) {
        f16x8 b = *(const f16x8*)&Bs[f*16 + lc][ks*32 + lp*8];
        acc[f] = __builtin_amdgcn_mfma_f32_16x16x32_f16(a, b, acc[f], 0, 0, 0);
      }
    }
  }
  #pragma unroll
  for (int f = 0; f < 4; ++f) {
    int col = n0 + f*16 + lc;
    float bsv = bias[col];
    #pragma unroll
    for (int rr = 0; rr < 4; ++rr) {
      int row = m0 + wv*16 + lp*4 + rr;
      float v = acc[f][rr] + bsv;
      if (OUTF32) ((float*)outp)[(size_t)row * EE + col] = v;
      else        ((f16*)outp)[(size_t)row * EE + col] = (f16)v;
    }
  }
}

// gather variant: A rows from mem[idx[row]]; AF16: A already f16, else f32 -> f16 inline
template <int AF16>
__global__ __launch_bounds__(256) void k_gemm_g(const int* __restrict__ gidx, const void* __restrict__ Asrc,
                                                const f16* __restrict__ B, const float* __restrict__ bias,
                                                f16* __restrict__ outp) {
  __shared__ f16 As[64][72];
  __shared__ f16 Bs[64][72];
  const int tid = threadIdx.x;
  const int wv = tid >> 6, l = tid & 63, lc = l & 15, lp = l >> 4;
  const int m0 = blockIdx.x * 64, n0 = blockIdx.y * 64;
  const int r = tid >> 2, co = (tid & 3) * 16;
  const int gi = gidx[m0 + r];
  f32x4 acc[4] = {{0,0,0,0},{0,0,0,0},{0,0,0,0},{0,0,0,0}};
  for (int kb = 0; kb < EE; kb += 64) {
    __syncthreads();
    if (AF16) {
      const f16* arow = (const f16*)Asrc + (size_t)gi * EE;
      *(f16x8*)&As[r][co]     = *(const f16x8*)(arow + kb + co);
      *(f16x8*)&As[r][co + 8] = *(const f16x8*)(arow + kb + co + 8);
    } else {
      const float* arow = (const float*)Asrc + (size_t)gi * EE;
      float4 x0 = *(const float4*)(arow + kb + co);
      float4 x1 = *(const float4*)(arow + kb + co + 4);
      float4 x2 = *(const float4*)(arow + kb + co + 8);
      float4 x3 = *(const float4*)(arow + kb + co + 12);
      f16x8 h0, h1;
      h0[0]=(f16)x0.x; h0[1]=(f16)x0.y; h0[2]=(f16)x0.z; h0[3]=(f16)x0.w;
      h0[4]=(f16)x1.x; h0[5]=(f16)x1.y; h0[6]=(f16)x1.z; h0[7]=(f16)x1.w;
      h1[0]=(f16)x2.x; h1[1]=(f16)x2.y; h1[2]=(f16)x2.z; h1[3]=(f16)x2.w;
      h1[4]=(f16)x3.x; h1[5]=(f16)x3.y; h1[6]=(f16)x3.z; h1[7]=(f16)x3.w;
      *(f16x8*)&As[r][co]     = h0;
      *(f16x8*)&As[r][co + 8] = h1;
    }
    *(float4*)&Bs[r][co]     = *(const float4*)(B + (size_t)(n0 + r) * EE + kb + co);
    *(float4*)&Bs[r][co + 8] = *(const float4*)(B + (size_t)(n0 + r) * EE + kb + co + 8);
    __syncthreads();
    #pragma unroll
    for (int ks = 0; ks < 2; ++ks) {
      f16x8 a = *(const f16x8*)&As[wv*16 + lc][ks*32 + lp*8];
      #pragma unroll
      for (int f = 0; f < 4; ++f) {
        f16x8 b = *(const f16x8*)&Bs[f*16 + lc][ks*32 + lp*8];
        acc[f] = __builtin_amdgcn_mfma_f32_16x16x32_f16(a, b, acc[f], 0, 0, 0);
      }
    }
  }
  #pragma unroll
  for (int f = 0; f < 4; ++f) {
    int col = n0 + f*16 + lc;
    float bsv = bias[col];
    #pragma unroll
    for (int rr = 0; rr < 4; ++rr) {
      int row = m0 + wv*16 + lp*4 + rr;
      outp[(size_t)row * EE + col] = (f16)(acc[f][rr] + bsv);
    }
  }
}

// ---------------- 5-key MHA (H=8, d=64), f32 compute ----------------
__global__ __launch_bounds__(256) void k_attn(const f16* __restrict__ qp, const f16* __restrict__ kp,
                                              const f16* __restrict__ vp, f16* __restrict__ ao) {
  int row = blockIdx.x * 4 + (threadIdx.x >> 6);
  int l = threadIdx.x & 63;
  int h = l >> 3, sl = l & 7;
  const f16* q = qp + (size_t)row * EE + h * 64 + sl * 8;
  float qv[8];
  #pragma unroll
  for (int i = 0; i < 8; ++i) qv[i] = (float)q[i];
  float sc[5];
  #pragma unroll
  for (int j = 0; j < 5; ++j) {
    const f16* kr = kp + ((size_t)row * 5 + j) * EE + h * 64 + sl * 8;
    float p = 0.f;
    #pragma unroll
    for (int i = 0; i < 8; ++i) p = fmaf(qv[i], (float)kr[i], p);
    p += __shfl_xor(p, 1); p += __shfl_xor(p, 2); p += __shfl_xor(p, 4);
    sc[j] = p * 0.125f;
  }
  float mx = fmaxf(fmaxf(fmaxf(sc[0], sc[1]), fmaxf(sc[2], sc[3])), sc[4]);
  float sum = 0.f;
  #pragma unroll
  for (int j = 0; j < 5; ++j) { sc[j] = __expf(sc[j] - mx); sum += sc[j]; }
  float inv = 1.0f / sum;
  float o[8] = {};
  #pragma unroll
  for (int j = 0; j < 5; ++j) {
    const f16* vr = vp + ((size_t)row * 5 + j) * EE + h * 64 + sl * 8;
    float aw = sc[j] * inv;
    #pragma unroll
    for (int i = 0; i < 8; ++i) o[i] = fmaf(aw, (float)vr[i], o[i]);
  }
  f16* dst = ao + (size_t)row * EE + h * 64 + sl * 8;
  #pragma unroll
  for (int i = 0; i < 8; ++i) dst[i] = (f16)o[i];
}

extern "C" void kernel_launch(void* const* d_in, const int* in_sizes, int n_in,
                              void* d_out, int out_size, void* d_ws, size_t ws_size,
                              hipStream_t stream) {
  const float* Q    = (const float*)d_in[0];
  const float* mk   = (const float*)d_in[1];
  const float* mv   = (const float*)d_in[2];
  const float* Wq   = (const float*)d_in[3];
  const float* bq   = (const float*)d_in[4];
  const float* Wk   = (const float*)d_in[5];
  const float* bk   = (const float*)d_in[6];
  const float* Wv   = (const float*)d_in[7];
  const float* bv   = (const float*)d_in[8];
  const float* Wiq  = (const float*)d_in[9];
  const float* Wik  = (const float*)d_in[10];
  const float* Wiv  = (const float*)d_in[11];
  const float* b_in = (const float*)d_in[12];
  const float* Wo   = (const float*)d_in[13];
  const float* bo   = (const float*)d_in[14];

  char* w = (char*)d_ws;
  size_t off = 0;
  auto alloc = [&](size_t bytes) { size_t o = off; off += (bytes + 255) & ~(size_t)255; return (void*)(w + o); };
  f16*    Kh     = (f16*)   alloc((size_t)NMEM * EE * 2);
  f16*    Qh     = (f16*)   alloc((size_t)BQ * EE * 2);   // dead after stage1 -> ao
  float*  sq32   = (float*) alloc((size_t)NMEM * 4);
  double* sq64   = (double*)alloc((size_t)NMEM * 8);
  f16*    Wc     = (f16*)   alloc((size_t)3 * EE * EE * 2);
  f16*    Wo16   = (f16*)   alloc((size_t)EE * EE * 2);
  float*  bc     = (float*) alloc((size_t)3 * EE * 4);
  int*    part_i = (int*)   alloc((size_t)BQ * NCAND * 4);
  float*  part_s = (float*) alloc((size_t)BQ * NCAND * 4);
  int*    idx5   = (int*)   alloc((size_t)BQ * 5 * 4);
  f16*    qp     = (f16*)   alloc((size_t)BQ * EE * 2);
  f16*    vp     = (f16*)   alloc((size_t)BQ * 5 * EE * 2);
  f16*    ao     = Qh;
  // big tier: separate kp + f16 value table -> gather projections read f16 (half traffic)
  size_t need_big = off + (size_t)NMEM * EE * 2 + (size_t)BQ * 5 * EE * 2 + 4096;
  bool big = (ws_size >= need_big);
  f16* Vh = nullptr;
  f16* kp;
  if (big) {
    Vh = (f16*)alloc((size_t)NMEM * EE * 2);
    kp = (f16*)alloc((size_t)BQ * 5 * EE * 2);
  } else {
    kp = Kh;   // overlay: Kh dead after stage1 in small tier
  }
  (void)in_sizes; (void)n_in; (void)out_size;

  k_prep_keys<<<NMEM / 4, 256, 0, stream>>>(mk, Kh, sq32, sq64);
  k_prep_f16<<<BQ / 4, 256, 0, stream>>>(Q, Qh);
  if (big) k_prep_f16<<<NMEM / 4, 256, 0, stream>>>(mv, Vh);
  k_compose<<<dim3(8, 8, 3), 256, 0, stream>>>(Wq, Wk, Wv, Wiq, Wik, Wiv, Wc);
  k_bias<<<3, 256, 0, stream>>>(Wiq, Wik, Wiv, bq, bk, bv, b_in, bc);
  k_cvtw<<<(EE * EE) / 256, 256, 0, stream>>>(Wo, Wo16);
  k_stage1<<<dim3(BQ / 128, NSEG), 256, 0, stream>>>(Qh, Kh, sq32, part_i, part_s);
  k_rescore<<<BQ, 64, 0, stream>>>(Q, mk, sq64, part_i, part_s, idx5);
  k_gemm<0><<<dim3(BQ / 64, 8), 256, 0, stream>>>(Qh, Wc, bc, qp);
  if (big) {
    k_gemm_g<1><<<dim3(BQ * 5 / 64, 8), 256, 0, stream>>>(idx5, Kh, Wc + (size_t)EE * EE, bc + EE, kp);
    k_gemm_g<1><<<dim3(BQ * 5 / 64, 8), 256, 0, stream>>>(idx5, Vh, Wc + (size_t)2 * EE * EE, bc + 2 * EE, vp);
  } else {
    k_gemm_g<0><<<dim3(BQ * 5 / 64, 8), 256, 0, stream>>>(idx5, mk, Wc + (size_t)EE * EE, bc + EE, kp);
    k_gemm_g<0><<<dim3(BQ * 5 / 64, 8), 256, 0, stream>>>(idx5, mv, Wc + (size_t)2 * EE * EE, bc + 2 * EE, vp);
  }
  k_attn<<<BQ / 4, 256, 0, stream>>>(qp, kp, vp, ao);
  k_gemm<1><<<dim3(BQ / 64, 8), 256, 0, stream>>>(ao, Wo16, bo, (float*)d_out);
}

// Round 10
// 792.866 us; speedup vs baseline: 2.7504x; 1.0867x over previous
//
#include <hip/hip_runtime.h>
#include <hip/hip_bf16.h>
#include <hip/hip_fp16.h>

typedef _Float16 f16;
typedef _Float16 f16x8 __attribute__((ext_vector_type(8)));
typedef float f32x4 __attribute__((ext_vector_type(4)));

constexpr int EE     = 512;
constexpr int NMEM   = 50000;
constexpr int BQ     = 8192;
constexpr int NSEG   = 16;
constexpr int SEGLEN = NMEM / NSEG;              // 3125 (exact)
constexpr int KVT    = 32;                       // keys per tile
constexpr int NT32   = (SEGLEN + KVT - 1) / KVT; // 98
constexpr int NC     = 5;                        // candidates kept per segment
constexpr int NCAND  = NSEG * NC;                // 80
constexpr int NRES   = 10;                       // exact-rescored candidates

// generic->addrspace casts for global_load_lds
typedef const __attribute__((address_space(1))) unsigned char* gas_t;
typedef __attribute__((address_space(3))) unsigned char* las_t;
__device__ static inline void g2l16(const void* g, void* l) {
  __builtin_amdgcn_global_load_lds((gas_t)g, (las_t)l, 16, 0, 0);
}

// ---------------- prep: f32 -> fp16 keys + f64/f32 row norms ----------------
__global__ __launch_bounds__(256) void k_prep_keys(const float* __restrict__ mk,
                                                   f16* __restrict__ kh,
                                                   float* __restrict__ sq32,
                                                   double* __restrict__ sq64) {
  int row  = blockIdx.x * 4 + (threadIdx.x >> 6);
  int lane = threadIdx.x & 63;
  const float4* src = (const float4*)(mk + (size_t)row * EE) + lane * 2;
  float4 a = src[0], b = src[1];
  double s = (double)a.x*a.x + (double)a.y*a.y + (double)a.z*a.z + (double)a.w*a.w
           + (double)b.x*b.x + (double)b.y*b.y + (double)b.z*b.z + (double)b.w*b.w;
  f16x8 h;
  h[0]=(f16)a.x; h[1]=(f16)a.y; h[2]=(f16)a.z; h[3]=(f16)a.w;
  h[4]=(f16)b.x; h[5]=(f16)b.y; h[6]=(f16)b.z; h[7]=(f16)b.w;
  *((f16x8*)(kh + (size_t)row * EE) + lane) = h;
  #pragma unroll
  for (int o = 32; o > 0; o >>= 1) s += __shfl_down(s, o);
  if (lane == 0) { sq64[row] = s; sq32[row] = (float)s; }
}

// generic f32 -> f16 row copy (rows of EE)
__global__ __launch_bounds__(256) void k_prep_f16(const float* __restrict__ src,
                                                  f16* __restrict__ dst) {
  int row  = blockIdx.x * 4 + (threadIdx.x >> 6);
  int lane = threadIdx.x & 63;
  const float4* s = (const float4*)(src + (size_t)row * EE) + lane * 2;
  float4 a = s[0], b = s[1];
  f16x8 h;
  h[0]=(f16)a.x; h[1]=(f16)a.y; h[2]=(f16)a.z; h[3]=(f16)a.w;
  h[4]=(f16)b.x; h[5]=(f16)b.y; h[6]=(f16)b.z; h[7]=(f16)b.w;
  *((f16x8*)(dst + (size_t)row * EE) + lane) = h;
}

// ---------------- compose weights: Wc_m = Win_m @ W_m (f32 acc -> fp16 out) ----------------
__global__ __launch_bounds__(256) void k_compose(const float* __restrict__ Wq, const float* __restrict__ Wk,
                                                 const float* __restrict__ Wv, const float* __restrict__ Wiq,
                                                 const float* __restrict__ Wik, const float* __restrict__ Wiv,
                                                 f16* __restrict__ Wc) {
  int m = blockIdx.z;
  const float* A = (m == 0) ? Wiq : ((m == 1) ? Wik : Wiv);
  const float* B = (m == 0) ? Wq  : ((m == 1) ? Wk  : Wv);
  f16* C = Wc + (size_t)m * EE * EE;
  __shared__ float As[64][33];
  __shared__ float Bs[32][65];
  int i0 = blockIdx.x * 64, j0 = blockIdx.y * 64;
  int tx = threadIdx.x & 15, ty = threadIdx.x >> 4;
  float acc[4][4] = {};
  for (int kb = 0; kb < EE; kb += 32) {
    __syncthreads();
    #pragma unroll
    for (int v = 0; v < 8; ++v) {
      int idx = threadIdx.x + v * 256;
      As[idx >> 5][idx & 31] = A[(size_t)(i0 + (idx >> 5)) * EE + kb + (idx & 31)];
    }
    #pragma unroll
    for (int v = 0; v < 8; ++v) {
      int idx = threadIdx.x + v * 256;
      Bs[idx >> 6][idx & 63] = B[(size_t)(kb + (idx >> 6)) * EE + j0 + (idx & 63)];
    }
    __syncthreads();
    for (int t = 0; t < 32; ++t) {
      float av[4], bv[4];
      #pragma unroll
      for (int u = 0; u < 4; ++u) av[u] = As[ty*4+u][t];
      #pragma unroll
      for (int u = 0; u < 4; ++u) bv[u] = Bs[t][tx*4+u];
      #pragma unroll
      for (int a = 0; a < 4; ++a)
        #pragma unroll
        for (int b = 0; b < 4; ++b) acc[a][b] = fmaf(av[a], bv[b], acc[a][b]);
    }
  }
  #pragma unroll
  for (int a = 0; a < 4; ++a)
    #pragma unroll
    for (int b = 0; b < 4; ++b)
      C[(size_t)(i0 + ty*4 + a) * EE + j0 + tx*4 + b] = (f16)acc[a][b];
}

__global__ void k_bias(const float* __restrict__ Wiq, const float* __restrict__ Wik,
                       const float* __restrict__ Wiv, const float* __restrict__ bqv,
                       const float* __restrict__ bkv, const float* __restrict__ bvv,
                       const float* __restrict__ b_in, float* __restrict__ bc) {
  int m = blockIdx.x;
  const float* Wi = (m == 0) ? Wiq : ((m == 1) ? Wik : Wiv);
  const float* bb = (m == 0) ? bqv : ((m == 1) ? bkv : bvv);
  for (int i = threadIdx.x; i < EE; i += blockDim.x) {
    float s = 0.f;
    for (int t = 0; t < EE; ++t) s = fmaf(Wi[(size_t)i * EE + t], bb[t], s);
    bc[m * EE + i] = s + b_in[m * EE + i];
  }
}

__global__ void k_cvtw(const float* __restrict__ W, f16* __restrict__ Wo) {
  int i = blockIdx.x * 256 + threadIdx.x;
  Wo[i] = (f16)W[i];
}

// ---------------- stage 1: swapped-operand fp16 MFMA scores, register top-5 ----------------
// mfma(K_frag, Q_frag): lane holds qrow = lane&15, keys striped by lane>>4 and reg.
// Staging via global_load_lds (wave-uniform LDS base + lane*16B, row-contiguous).
// OOB keys poisoned through sqs (+6e38) -> no bound checks in hot loop.
__global__ __launch_bounds__(256, 2) void k_stage1(const f16* __restrict__ Qh,
                                                   const f16* __restrict__ Kh,
                                                   const float* __restrict__ sq32,
                                                   int* __restrict__ part_i,
                                                   float* __restrict__ part_s) {
  const int rb  = blockIdx.x;        // 0..63 (128 rows each)
  const int seg = blockIdx.y;        // 0..15
  const int tid = threadIdx.x;
  const int w   = tid >> 6;          // wave 0..3
  const int l   = tid & 63;
  const int lc  = l & 15, lp = l >> 4;
  const int seg_start = seg * SEGLEN;
  const int seg_end   = seg_start + SEGLEN;

  __shared__ f16   Bt[2][KVT * 520];
  __shared__ float sqs[2][KVT];

  const int rowbase = rb * 128 + w * 32;
  f16x8 a0[16], a1[16];
  {
    const f16* base0 = Qh + (size_t)(rowbase + lc) * EE + lp * 8;
    const f16* base1 = base0 + (size_t)16 * EE;
    #pragma unroll
    for (int ks = 0; ks < 16; ++ks) {
      asm volatile("global_load_dwordx4 %0, %1, off"
                   : "=v"(a0[ks]) : "v"(base0 + ks * 32) : "memory");
      asm volatile("global_load_dwordx4 %0, %1, off"
                   : "=v"(a1[ks]) : "v"(base1 + ks * 32) : "memory");
    }
    asm volatile("s_waitcnt vmcnt(0)" ::: "memory");
    __builtin_amdgcn_sched_barrier(0);
  }

  float ts0[NC], ts1[NC]; int ti0[NC], ti1[NC];
  #pragma unroll
  for (int i = 0; i < NC; ++i) {
    ts0[i] = -3.0e38f; ti0[i] = 0;
    ts1[i] = -3.0e38f; ti1[i] = 0;
  }

#define INS(TS, TI, SV, IV) do { \
    if ((SV) > TS[NC-1]) { \
      TS[NC-1] = (SV); TI[NC-1] = (IV); \
      _Pragma("unroll") \
      for (int _i = NC - 1; _i > 0; --_i) { \
        if (TS[_i] > TS[_i-1]) { \
          float _tf = TS[_i]; TS[_i] = TS[_i-1]; TS[_i-1] = _tf; \
          int   _tx = TI[_i]; TI[_i] = TI[_i-1]; TI[_i-1] = _tx; \
        } \
      } \
    } \
  } while (0)

  // stage tile tt into buffer buf: 8 rows per wave, direct global->LDS
  #define STAGE(buf, tt) do { \
      int kk = seg_start + (tt) * KVT; \
      _Pragma("unroll") \
      for (int j = 0; j < 8; ++j) { \
        int key = kk + w * 8 + j; \
        key = key < NMEM ? key : NMEM - 1; \
        g2l16(Kh + (size_t)key * EE + l * 8, &Bt[buf][(w*8 + j) * 520]); \
      } \
      if (tid < KVT) { \
        int kq = kk + tid; \
        float v = 6.0e38f; \
        if (kq < seg_end) v = sq32[kq]; \
        sqs[buf][tid] = v; \
      } \
    } while (0)

  STAGE(0, 0);
  for (int t = 0; t < NT32; ++t) {
    const int c = t & 1;
    __syncthreads();               // drains vmcnt: buf[c] staged; prior reads of buf[c^1] done
    if (t + 1 < NT32) STAGE(c ^ 1, t + 1);   // in-flight during compute; drained at next barrier

    f32x4 A00 = {0,0,0,0}, A01 = {0,0,0,0}, A10 = {0,0,0,0}, A11 = {0,0,0,0};
    #pragma unroll
    for (int ks = 0; ks < 16; ++ks) {
      f16x8 kf0 = *(const f16x8*)&Bt[c][lc * 520 + ks * 32 + lp * 8];
      f16x8 kf1 = *(const f16x8*)&Bt[c][(16 + lc) * 520 + ks * 32 + lp * 8];
      A00 = __builtin_amdgcn_mfma_f32_16x16x32_f16(kf0, a0[ks], A00, 0, 0, 0);
      A01 = __builtin_amdgcn_mfma_f32_16x16x32_f16(kf0, a1[ks], A01, 0, 0, 0);
      A10 = __builtin_amdgcn_mfma_f32_16x16x32_f16(kf1, a0[ks], A10, 0, 0, 0);
      A11 = __builtin_amdgcn_mfma_f32_16x16x32_f16(kf1, a1[ks], A11, 0, 0, 0);
    }
    // epilogue: vector scores (poisoned sqs makes OOB keys -6e38), register inserts
    f32x4 q0 = *(const f32x4*)&sqs[c][lp * 4];
    f32x4 q1 = *(const f32x4*)&sqs[c][16 + lp * 4];
    f32x4 s00 = 2.0f * A00 - q0;
    f32x4 s01 = 2.0f * A01 - q0;
    f32x4 s10 = 2.0f * A10 - q1;
    f32x4 s11 = 2.0f * A11 - q1;
    const int kb = seg_start + t * KVT;
    const int b0 = kb + lp * 4;
    const int b1 = b0 + 16;
    #pragma unroll
    for (int r = 0; r < 4; ++r) {
      INS(ts0, ti0, s00[r], b0 + r);
      INS(ts0, ti0, s10[r], b1 + r);
      INS(ts1, ti1, s01[r], b0 + r);
      INS(ts1, ti1, s11[r], b1 + r);
    }
  }
  #undef STAGE

  // merge key-stripes: lanes {lc, lc+16, lc+32, lc+48} hold disjoint stripes of same q-rows
  #pragma unroll
  for (int d = 16; d <= 32; d <<= 1) {
    float os[NC]; int oi[NC];
    #pragma unroll
    for (int i = 0; i < NC; ++i) { os[i] = __shfl_xor(ts0[i], d); oi[i] = __shfl_xor(ti0[i], d); }
    #pragma unroll
    for (int j = 0; j < NC; ++j) INS(ts0, ti0, os[j], oi[j]);
    #pragma unroll
    for (int i = 0; i < NC; ++i) { os[i] = __shfl_xor(ts1[i], d); oi[i] = __shfl_xor(ti1[i], d); }
    #pragma unroll
    for (int j = 0; j < NC; ++j) INS(ts1, ti1, os[j], oi[j]);
  }
#undef INS
  if (l < 16) {
    int row = rowbase + lc;
    #pragma unroll
    for (int i = 0; i < NC; ++i) {
      part_i[(size_t)row * NCAND + seg * NC + i] = ti0[i];
      part_s[(size_t)row * NCAND + seg * NC + i] = ts0[i];
    }
  } else if (l < 32) {
    int row = rowbase + 16 + lc;
    #pragma unroll
    for (int i = 0; i < NC; ++i) {
      part_i[(size_t)row * NCAND + seg * NC + i] = ti1[i];
      part_s[(size_t)row * NCAND + seg * NC + i] = ts1[i];
    }
  }
}

// ---------------- stage 2: noisy top-10 of 80, exact f64 rescore -> top-5 ----------------
__global__ __launch_bounds__(64) void k_rescore(const float* __restrict__ Q,
                                                const float* __restrict__ mk,
                                                const double* __restrict__ sq64,
                                                const int* __restrict__ part_i,
                                                const float* __restrict__ part_s,
                                                int* __restrict__ idx5) {
  const int row = blockIdx.x;
  const int l = threadIdx.x;
  const float* Qr = Q + (size_t)row * EE;
  float q[8];
  #pragma unroll
  for (int i = 0; i < 8; ++i) q[i] = Qr[l + 64*i];
  float s0 = part_s[(size_t)row * NCAND + l];
  int   i0 = part_i[(size_t)row * NCAND + l];
  float s1 = (l < NCAND - 64) ? part_s[(size_t)row * NCAND + 64 + l] : -3.0e38f;
  int   i1 = (l < NCAND - 64) ? part_i[(size_t)row * NCAND + 64 + l] : 0;

  double bs[5] = {-1e300, -1e300, -1e300, -1e300, -1e300};
  int    bi[5] = {0, 0, 0, 0, 0};
  #pragma unroll
  for (int p = 0; p < NRES; ++p) {
    bool pick0 = (s0 >= s1);
    float m  = pick0 ? s0 : s1;
    int   mi = pick0 ? i0 : i1;
    int   code = (l << 1) | (pick0 ? 0 : 1);
    #pragma unroll
    for (int o = 32; o > 0; o >>= 1) {
      float mo = __shfl_xor(m, o);
      int   io = __shfl_xor(mi, o);
      int   co = __shfl_xor(code, o);
      if (mo > m || (mo == m && co < code)) { m = mo; mi = io; code = co; }
    }
    if ((code >> 1) == l) { if (code & 1) s1 = -3.0e38f; else s0 = -3.0e38f; }
    const float* kr = mk + (size_t)mi * EE;
    double pd = 0.0;
    #pragma unroll
    for (int i = 0; i < 8; ++i) pd += (double)q[i] * (double)kr[l + 64*i];
    #pragma unroll
    for (int o = 32; o > 0; o >>= 1) pd += __shfl_down(pd, o);
    if (l == 0) {
      double s = 2.0 * pd - sq64[mi];
      if (s > bs[4]) {
        bs[4] = s; bi[4] = mi;
        #pragma unroll
        for (int i = 4; i > 0; --i) {
          if (bs[i] > bs[i-1]) {
            double tf = bs[i]; bs[i] = bs[i-1]; bs[i-1] = tf;
            int    tx = bi[i]; bi[i] = bi[i-1]; bi[i-1] = tx;
          }
        }
      }
    }
  }
  if (l == 0) {
    #pragma unroll
    for (int i = 0; i < 5; ++i) idx5[(size_t)row*5 + i] = bi[i];
  }
}

// ---------------- fp16 MFMA GEMM: C = A @ B^T + bias (64x64 tile) ----------------
template <int OUTF32>
__global__ __launch_bounds__(256) void k_gemm(const f16* __restrict__ A, const f16* __restrict__ B,
                                              const float* __restrict__ bias, void* __restrict__ outp) {
  __shared__ f16 As[64][72];
  __shared__ f16 Bs[64][72];
  const int tid = threadIdx.x;
  const int wv = tid >> 6, l = tid & 63, lc = l & 15, lp = l >> 4;
  const int m0 = blockIdx.x * 64, n0 = blockIdx.y * 64;
  const int r = tid >> 2, co = (tid & 3) * 16;
  f32x4 acc[4] = {{0,0,0,0},{0,0,0,0},{0,0,0,0},{0,0,0,0}};
  for (int kb = 0; kb < EE; kb += 64) {
    __syncthreads();
    *(float4*)&As[r][co]     = *(const float4*)(A + (size_t)(m0 + r) * EE + kb + co);
    *(float4*)&As[r][co + 8] = *(const float4*)(A + (size_t)(m0 + r) * EE + kb + co + 8);
    *(float4*)&Bs[r][co]     = *(const float4*)(B + (size_t)(n0 + r) * EE + kb + co);
    *(float4*)&Bs[r][co + 8] = *(const float4*)(B + (size_t)(n0 + r) * EE + kb + co + 8);
    __syncthreads();
    #pragma unroll
    for (int ks = 0; ks < 2; ++ks) {
      f16x8 a = *(const f16x8*)&As[wv*16 + lc][ks*32 + lp*8];
      #pragma unroll
      for (int f = 0; f < 4; ++f) {
        f16x8 b = *(const f16x8*)&Bs[f*16 + lc][ks*32 + lp*8];
        acc[f] = __builtin_amdgcn_mfma_f32_16x16x32_f16(a, b, acc[f], 0, 0, 0);
      }
    }
  }
  #pragma unroll
  for (int f = 0; f < 4; ++f) {
    int col = n0 + f*16 + lc;
    float bsv = bias[col];
    #pragma unroll
    for (int rr = 0; rr < 4; ++rr) {
      int row = m0 + wv*16 + lp*4 + rr;
      float v = acc[f][rr] + bsv;
      if (OUTF32) ((float*)outp)[(size_t)row * EE + col] = v;
      else        ((f16*)outp)[(size_t)row * EE + col] = (f16)v;
    }
  }
}

// gather variant: A rows from mem[idx[row]]; AF16: A already f16, else f32 -> f16 inline
template <int AF16>
__global__ __launch_bounds__(256) void k_gemm_g(const int* __restrict__ gidx, const void* __restrict__ Asrc,
                                                const f16* __restrict__ B, const float* __restrict__ bias,
                                                f16* __restrict__ outp) {
  __shared__ f16 As[64][72];
  __shared__ f16 Bs[64][72];
  const int tid = threadIdx.x;
  const int wv = tid >> 6, l = tid & 63, lc = l & 15, lp = l >> 4;
  const int m0 = blockIdx.x * 64, n0 = blockIdx.y * 64;
  const int r = tid >> 2, co = (tid & 3) * 16;
  const int gi = gidx[m0 + r];
  f32x4 acc[4] = {{0,0,0,0},{0,0,0,0},{0,0,0,0},{0,0,0,0}};
  for (int kb = 0; kb < EE; kb += 64) {
    __syncthreads();
    if (AF16) {
      const f16* arow = (const f16*)Asrc + (size_t)gi * EE;
      *(f16x8*)&As[r][co]     = *(const f16x8*)(arow + kb + co);
      *(f16x8*)&As[r][co + 8] = *(const f16x8*)(arow + kb + co + 8);
    } else {
      const float* arow = (const float*)Asrc + (size_t)gi * EE;
      float4 x0 = *(const float4*)(arow + kb + co);
      float4 x1 = *(const float4*)(arow + kb + co + 4);
      float4 x2 = *(const float4*)(arow + kb + co + 8);
      float4 x3 = *(const float4*)(arow + kb + co + 12);
      f16x8 h0, h1;
      h0[0]=(f16)x0.x; h0[1]=(f16)x0.y; h0[2]=(f16)x0.z; h0[3]=(f16)x0.w;
      h0[4]=(f16)x1.x; h0[5]=(f16)x1.y; h0[6]=(f16)x1.z; h0[7]=(f16)x1.w;
      h1[0]=(f16)x2.x; h1[1]=(f16)x2.y; h1[2]=(f16)x2.z; h1[3]=(f16)x2.w;
      h1[4]=(f16)x3.x; h1[5]=(f16)x3.y; h1[6]=(f16)x3.z; h1[7]=(f16)x3.w;
      *(f16x8*)&As[r][co]     = h0;
      *(f16x8*)&As[r][co + 8] = h1;
    }
    *(float4*)&Bs[r][co]     = *(const float4*)(B + (size_t)(n0 + r) * EE + kb + co);
    *(float4*)&Bs[r][co + 8] = *(const float4*)(B + (size_t)(n0 + r) * EE + kb + co + 8);
    __syncthreads();
    #pragma unroll
    for (int ks = 0; ks < 2; ++ks) {
      f16x8 a = *(const f16x8*)&As[wv*16 + lc][ks*32 + lp*8];
      #pragma unroll
      for (int f = 0; f < 4; ++f) {
        f16x8 b = *(const f16x8*)&Bs[f*16 + lc][ks*32 + lp*8];
        acc[f] = __builtin_amdgcn_mfma_f32_16x16x32_f16(a, b, acc[f], 0, 0, 0);
      }
    }
  }
  #pragma unroll
  for (int f = 0; f < 4; ++f) {
    int col = n0 + f*16 + lc;
    float bsv = bias[col];
    #pragma unroll
    for (int rr = 0; rr < 4; ++rr) {
      int row = m0 + wv*16 + lp*4 + rr;
      outp[(size_t)row * EE + col] = (f16)(acc[f][rr] + bsv);
    }
  }
}

// ---------------- 5-key MHA (H=8, d=64), f32 compute ----------------
__global__ __launch_bounds__(256) void k_attn(const f16* __restrict__ qp, const f16* __restrict__ kp,
                                              const f16* __restrict__ vp, f16* __restrict__ ao) {
  int row = blockIdx.x * 4 + (threadIdx.x >> 6);
  int l = threadIdx.x & 63;
  int h = l >> 3, sl = l & 7;
  const f16* q = qp + (size_t)row * EE + h * 64 + sl * 8;
  float qv[8];
  #pragma unroll
  for (int i = 0; i < 8; ++i) qv[i] = (float)q[i];
  float sc[5];
  #pragma unroll
  for (int j = 0; j < 5; ++j) {
    const f16* kr = kp + ((size_t)row * 5 + j) * EE + h * 64 + sl * 8;
    float p = 0.f;
    #pragma unroll
    for (int i = 0; i < 8; ++i) p = fmaf(qv[i], (float)kr[i], p);
    p += __shfl_xor(p, 1); p += __shfl_xor(p, 2); p += __shfl_xor(p, 4);
    sc[j] = p * 0.125f;
  }
  float mx = fmaxf(fmaxf(fmaxf(sc[0], sc[1]), fmaxf(sc[2], sc[3])), sc[4]);
  float sum = 0.f;
  #pragma unroll
  for (int j = 0; j < 5; ++j) { sc[j] = __expf(sc[j] - mx); sum += sc[j]; }
  float inv = 1.0f / sum;
  float o[8] = {};
  #pragma unroll
  for (int j = 0; j < 5; ++j) {
    const f16* vr = vp + ((size_t)row * 5 + j) * EE + h * 64 + sl * 8;
    float aw = sc[j] * inv;
    #pragma unroll
    for (int i = 0; i < 8; ++i) o[i] = fmaf(aw, (float)vr[i], o[i]);
  }
  f16* dst = ao + (size_t)row * EE + h * 64 + sl * 8;
  #pragma unroll
  for (int i = 0; i < 8; ++i) dst[i] = (f16)o[i];
}

extern "C" void kernel_launch(void* const* d_in, const int* in_sizes, int n_in,
                              void* d_out, int out_size, void* d_ws, size_t ws_size,
                              hipStream_t stream) {
  const float* Q    = (const float*)d_in[0];
  const float* mk   = (const float*)d_in[1];
  const float* mv   = (const float*)d_in[2];
  const float* Wq   = (const float*)d_in[3];
  const float* bq   = (const float*)d_in[4];
  const float* Wk   = (const float*)d_in[5];
  const float* bk   = (const float*)d_in[6];
  const float* Wv   = (const float*)d_in[7];
  const float* bv   = (const float*)d_in[8];
  const float* Wiq  = (const float*)d_in[9];
  const float* Wik  = (const float*)d_in[10];
  const float* Wiv  = (const float*)d_in[11];
  const float* b_in = (const float*)d_in[12];
  const float* Wo   = (const float*)d_in[13];
  const float* bo   = (const float*)d_in[14];

  char* w = (char*)d_ws;
  size_t off = 0;
  auto alloc = [&](size_t bytes) { size_t o = off; off += (bytes + 255) & ~(size_t)255; return (void*)(w + o); };
  f16*    Kh     = (f16*)   alloc((size_t)NMEM * EE * 2);
  f16*    Qh     = (f16*)   alloc((size_t)BQ * EE * 2);   // dead after stage1 -> ao
  float*  sq32   = (float*) alloc((size_t)NMEM * 4);
  double* sq64   = (double*)alloc((size_t)NMEM * 8);
  f16*    Wc     = (f16*)   alloc((size_t)3 * EE * EE * 2);
  f16*    Wo16   = (f16*)   alloc((size_t)EE * EE * 2);
  float*  bc     = (float*) alloc((size_t)3 * EE * 4);
  int*    part_i = (int*)   alloc((size_t)BQ * NCAND * 4);
  float*  part_s = (float*) alloc((size_t)BQ * NCAND * 4);
  int*    idx5   = (int*)   alloc((size_t)BQ * 5 * 4);
  f16*    qp     = (f16*)   alloc((size_t)BQ * EE * 2);
  f16*    vp     = (f16*)   alloc((size_t)BQ * 5 * EE * 2);
  f16*    ao     = Qh;
  // big tier: separate kp + f16 value table -> gather projections read f16 (half traffic)
  size_t need_big = off + (size_t)NMEM * EE * 2 + (size_t)BQ * 5 * EE * 2 + 4096;
  bool big = (ws_size >= need_big);
  f16* Vh = nullptr;
  f16* kp;
  if (big) {
    Vh = (f16*)alloc((size_t)NMEM * EE * 2);
    kp = (f16*)alloc((size_t)BQ * 5 * EE * 2);
  } else {
    kp = Kh;   // overlay: Kh dead after stage1 in small tier
  }
  (void)in_sizes; (void)n_in; (void)out_size;

  k_prep_keys<<<NMEM / 4, 256, 0, stream>>>(mk, Kh, sq32, sq64);
  k_prep_f16<<<BQ / 4, 256, 0, stream>>>(Q, Qh);
  if (big) k_prep_f16<<<NMEM / 4, 256, 0, stream>>>(mv, Vh);
  k_compose<<<dim3(8, 8, 3), 256, 0, stream>>>(Wq, Wk, Wv, Wiq, Wik, Wiv, Wc);
  k_bias<<<3, 256, 0, stream>>>(Wiq, Wik, Wiv, bq, bk, bv, b_in, bc);
  k_cvtw<<<(EE * EE) / 256, 256, 0, stream>>>(Wo, Wo16);
  k_stage1<<<dim3(BQ / 128, NSEG), 256, 0, stream>>>(Qh, Kh, sq32, part_i, part_s);
  k_rescore<<<BQ, 64, 0, stream>>>(Q, mk, sq64, part_i, part_s, idx5);
  k_gemm<0><<<dim3(BQ / 64, 8), 256, 0, stream>>>(Qh, Wc, bc, qp);
  if (big) {
    k_gemm_g<1><<<dim3(BQ * 5 / 64, 8), 256, 0, stream>>>(idx5, Kh, Wc + (size_t)EE * EE, bc + EE, kp);
    k_gemm_g<1><<<dim3(BQ * 5 / 64, 8), 256, 0, stream>>>(idx5, Vh, Wc + (size_t)2 * EE * EE, bc + 2 * EE, vp);
  } else {
    k_gemm_g<0><<<dim3(BQ * 5 / 64, 8), 256, 0, stream>>>(idx5, mk, Wc + (size_t)EE * EE, bc + EE, kp);
    k_gemm_g<0><<<dim3(BQ * 5 / 64, 8), 256, 0, stream>>>(idx5, mv, Wc + (size_t)2 * EE * EE, bc + 2 * EE, vp);
  }
  k_attn<<<BQ / 4, 256, 0, stream>>>(qp, kp, vp, ao);
  k_gemm<1><<<dim3(BQ / 64, 8), 256, 0, stream>>>(ao, Wo16, bo, (float*)d_out);
}

// Round 11
// 746.627 us; speedup vs baseline: 2.9208x; 1.0619x over previous
//
#include <hip/hip_runtime.h>
#include <hip/hip_bf16.h>
#include <hip/hip_fp16.h>

typedef _Float16 f16;
typedef _Float16 f16x8 __attribute__((ext_vector_type(8)));
typedef float f32x4 __attribute__((ext_vector_type(4)));

constexpr int EE     = 512;
constexpr int NMEM   = 50000;
constexpr int BQ     = 8192;
constexpr int NSEG   = 16;
constexpr int SEGLEN = NMEM / NSEG;              // 3125 (exact)
constexpr int KVT    = 32;                       // keys per tile
constexpr int NT32   = (SEGLEN + KVT - 1) / KVT; // 98
constexpr int NC     = 5;                        // candidates kept per segment
constexpr int NCAND  = NSEG * NC;                // 80
constexpr int NRES   = 10;                       // exact-rescored candidates

// generic->addrspace casts for global_load_lds
typedef const __attribute__((address_space(1))) unsigned char* gas_t;
typedef __attribute__((address_space(3))) unsigned char* las_t;
__device__ static inline void g2l16(const void* g, void* l) {
  __builtin_amdgcn_global_load_lds((gas_t)g, (las_t)l, 16, 0, 0);
}

// pack 12-bit local index into low mantissa bits of score (compare-as-float safe:
// perturbation <= 0.125 at |score|~500, far below rank-5..10 gaps; rescore is exact)
__device__ static inline float pack_si(float s, int li) {
  return __uint_as_float((__float_as_uint(s) & 0xFFFFF000u) | (unsigned)li);
}

// ---------------- prep: f32 -> fp16 keys + f64/f32 row norms ----------------
__global__ __launch_bounds__(256) void k_prep_keys(const float* __restrict__ mk,
                                                   f16* __restrict__ kh,
                                                   float* __restrict__ sq32,
                                                   double* __restrict__ sq64) {
  int row  = blockIdx.x * 4 + (threadIdx.x >> 6);
  int lane = threadIdx.x & 63;
  const float4* src = (const float4*)(mk + (size_t)row * EE) + lane * 2;
  float4 a = src[0], b = src[1];
  double s = (double)a.x*a.x + (double)a.y*a.y + (double)a.z*a.z + (double)a.w*a.w
           + (double)b.x*b.x + (double)b.y*b.y + (double)b.z*b.z + (double)b.w*b.w;
  f16x8 h;
  h[0]=(f16)a.x; h[1]=(f16)a.y; h[2]=(f16)a.z; h[3]=(f16)a.w;
  h[4]=(f16)b.x; h[5]=(f16)b.y; h[6]=(f16)b.z; h[7]=(f16)b.w;
  *((f16x8*)(kh + (size_t)row * EE) + lane) = h;
  #pragma unroll
  for (int o = 32; o > 0; o >>= 1) s += __shfl_down(s, o);
  if (lane == 0) { sq64[row] = s; sq32[row] = (float)s; }
}

// generic f32 -> f16 row copy (rows of EE)
__global__ __launch_bounds__(256) void k_prep_f16(const float* __restrict__ src,
                                                  f16* __restrict__ dst) {
  int row  = blockIdx.x * 4 + (threadIdx.x >> 6);
  int lane = threadIdx.x & 63;
  const float4* s = (const float4*)(src + (size_t)row * EE) + lane * 2;
  float4 a = s[0], b = s[1];
  f16x8 h;
  h[0]=(f16)a.x; h[1]=(f16)a.y; h[2]=(f16)a.z; h[3]=(f16)a.w;
  h[4]=(f16)b.x; h[5]=(f16)b.y; h[6]=(f16)b.z; h[7]=(f16)b.w;
  *((f16x8*)(dst + (size_t)row * EE) + lane) = h;
}

// ---------------- compose weights: Wc_m = Win_m @ W_m (f32 acc -> fp16 out) ----------------
__global__ __launch_bounds__(256) void k_compose(const float* __restrict__ Wq, const float* __restrict__ Wk,
                                                 const float* __restrict__ Wv, const float* __restrict__ Wiq,
                                                 const float* __restrict__ Wik, const float* __restrict__ Wiv,
                                                 f16* __restrict__ Wc) {
  int m = blockIdx.z;
  const float* A = (m == 0) ? Wiq : ((m == 1) ? Wik : Wiv);
  const float* B = (m == 0) ? Wq  : ((m == 1) ? Wk  : Wv);
  f16* C = Wc + (size_t)m * EE * EE;
  __shared__ float As[64][33];
  __shared__ float Bs[32][65];
  int i0 = blockIdx.x * 64, j0 = blockIdx.y * 64;
  int tx = threadIdx.x & 15, ty = threadIdx.x >> 4;
  float acc[4][4] = {};
  for (int kb = 0; kb < EE; kb += 32) {
    __syncthreads();
    #pragma unroll
    for (int v = 0; v < 8; ++v) {
      int idx = threadIdx.x + v * 256;
      As[idx >> 5][idx & 31] = A[(size_t)(i0 + (idx >> 5)) * EE + kb + (idx & 31)];
    }
    #pragma unroll
    for (int v = 0; v < 8; ++v) {
      int idx = threadIdx.x + v * 256;
      Bs[idx >> 6][idx & 63] = B[(size_t)(kb + (idx >> 6)) * EE + j0 + (idx & 63)];
    }
    __syncthreads();
    for (int t = 0; t < 32; ++t) {
      float av[4], bv[4];
      #pragma unroll
      for (int u = 0; u < 4; ++u) av[u] = As[ty*4+u][t];
      #pragma unroll
      for (int u = 0; u < 4; ++u) bv[u] = Bs[t][tx*4+u];
      #pragma unroll
      for (int a = 0; a < 4; ++a)
        #pragma unroll
        for (int b = 0; b < 4; ++b) acc[a][b] = fmaf(av[a], bv[b], acc[a][b]);
    }
  }
  #pragma unroll
  for (int a = 0; a < 4; ++a)
    #pragma unroll
    for (int b = 0; b < 4; ++b)
      C[(size_t)(i0 + ty*4 + a) * EE + j0 + tx*4 + b] = (f16)acc[a][b];
}

__global__ void k_bias(const float* __restrict__ Wiq, const float* __restrict__ Wik,
                       const float* __restrict__ Wiv, const float* __restrict__ bqv,
                       const float* __restrict__ bkv, const float* __restrict__ bvv,
                       const float* __restrict__ b_in, float* __restrict__ bc) {
  int m = blockIdx.x;
  const float* Wi = (m == 0) ? Wiq : ((m == 1) ? Wik : Wiv);
  const float* bb = (m == 0) ? bqv : ((m == 1) ? bkv : bvv);
  for (int i = threadIdx.x; i < EE; i += blockDim.x) {
    float s = 0.f;
    for (int t = 0; t < EE; ++t) s = fmaf(Wi[(size_t)i * EE + t], bb[t], s);
    bc[m * EE + i] = s + b_in[m * EE + i];
  }
}

__global__ void k_cvtw(const float* __restrict__ W, f16* __restrict__ Wo) {
  int i = blockIdx.x * 256 + threadIdx.x;
  Wo[i] = (f16)W[i];
}

// ---------------- stage 1: swapped-operand fp16 MFMA scores, packed register top-5 ----------------
__global__ __launch_bounds__(256, 2) void k_stage1(const f16* __restrict__ Qh,
                                                   const f16* __restrict__ Kh,
                                                   const float* __restrict__ sq32,
                                                   int* __restrict__ part_i,
                                                   float* __restrict__ part_s) {
  const int rb  = blockIdx.x;        // 0..63 (128 rows each)
  const int seg = blockIdx.y;        // 0..15
  const int tid = threadIdx.x;
  const int w   = tid >> 6;          // wave 0..3
  const int l   = tid & 63;
  const int lc  = l & 15, lp = l >> 4;
  const int seg_start = seg * SEGLEN;
  const int seg_end   = seg_start + SEGLEN;

  __shared__ f16   Bt[2][KVT * 520];
  __shared__ float sqs[2][KVT];

  const int rowbase = rb * 128 + w * 32;
  f16x8 a0[16], a1[16];
  {
    const f16* base0 = Qh + (size_t)(rowbase + lc) * EE + lp * 8;
    const f16* base1 = base0 + (size_t)16 * EE;
    #pragma unroll
    for (int ks = 0; ks < 16; ++ks) {
      asm volatile("global_load_dwordx4 %0, %1, off"
                   : "=v"(a0[ks]) : "v"(base0 + ks * 32) : "memory");
      asm volatile("global_load_dwordx4 %0, %1, off"
                   : "=v"(a1[ks]) : "v"(base1 + ks * 32) : "memory");
    }
    asm volatile("s_waitcnt vmcnt(0)" ::: "memory");
    __builtin_amdgcn_sched_barrier(0);
  }

  // packed lists: ts0 -> qrow rowbase+lc, ts1 -> qrow rowbase+16+lc (key-striped by lp)
  float ts0[NC], ts1[NC];
  #pragma unroll
  for (int i = 0; i < NC; ++i) { ts0[i] = -3.0e38f; ts1[i] = -3.0e38f; }

// ballot-guarded branchy insert: skip is wave-uniform (scalar branch), insert is a
// single fmax/fmin bubble pass on the packed floats (no index swaps).
#define INS1(TS, PV) do { \
    if (__ballot((PV) > TS[NC-1])) { \
      float _nv = ((PV) > TS[NC-1]) ? (PV) : TS[NC-1]; \
      TS[NC-1] = _nv; \
      _Pragma("unroll") \
      for (int _i = NC - 1; _i > 0; --_i) { \
        float _mx = fmaxf(TS[_i], TS[_i-1]); \
        float _mn = fminf(TS[_i], TS[_i-1]); \
        TS[_i-1] = _mx; TS[_i] = _mn; \
      } \
    } \
  } while (0)

  // stage tile tt into buffer buf: 8 rows per wave, direct global->LDS
  #define STAGE(buf, tt) do { \
      int kk = seg_start + (tt) * KVT; \
      _Pragma("unroll") \
      for (int j = 0; j < 8; ++j) { \
        int key = kk + w * 8 + j; \
        key = key < NMEM ? key : NMEM - 1; \
        g2l16(Kh + (size_t)key * EE + l * 8, &Bt[buf][(w*8 + j) * 520]); \
      } \
      if (tid < KVT) { \
        int kq = kk + tid; \
        float v = 6.0e38f; \
        if (kq < seg_end) v = sq32[kq]; \
        sqs[buf][tid] = v; \
      } \
    } while (0)

  STAGE(0, 0);
  for (int t = 0; t < NT32; ++t) {
    const int c = t & 1;
    __syncthreads();               // drains vmcnt: buf[c] staged; prior reads of buf[c^1] done
    if (t + 1 < NT32) STAGE(c ^ 1, t + 1);   // in-flight during compute; drained at next barrier

    f32x4 A00 = {0,0,0,0}, A01 = {0,0,0,0}, A10 = {0,0,0,0}, A11 = {0,0,0,0};
    #pragma unroll
    for (int ks = 0; ks < 16; ++ks) {
      f16x8 kf0 = *(const f16x8*)&Bt[c][lc * 520 + ks * 32 + lp * 8];
      f16x8 kf1 = *(const f16x8*)&Bt[c][(16 + lc) * 520 + ks * 32 + lp * 8];
      A00 = __builtin_amdgcn_mfma_f32_16x16x32_f16(kf0, a0[ks], A00, 0, 0, 0);
      A01 = __builtin_amdgcn_mfma_f32_16x16x32_f16(kf0, a1[ks], A01, 0, 0, 0);
      A10 = __builtin_amdgcn_mfma_f32_16x16x32_f16(kf1, a0[ks], A10, 0, 0, 0);
      A11 = __builtin_amdgcn_mfma_f32_16x16x32_f16(kf1, a1[ks], A11, 0, 0, 0);
    }
    // epilogue: vector scores (poisoned sqs makes OOB keys -6e38), packed inserts
    f32x4 q0 = *(const f32x4*)&sqs[c][lp * 4];
    f32x4 q1 = *(const f32x4*)&sqs[c][16 + lp * 4];
    f32x4 s00 = 2.0f * A00 - q0;
    f32x4 s01 = 2.0f * A01 - q0;
    f32x4 s10 = 2.0f * A10 - q1;
    f32x4 s11 = 2.0f * A11 - q1;
    const int li0 = t * KVT + lp * 4;   // 12-bit local key index (<= 3135)
    const int li1 = li0 + 16;
    #pragma unroll
    for (int r = 0; r < 4; ++r) {
      INS1(ts0, pack_si(s00[r], li0 + r));
      INS1(ts0, pack_si(s10[r], li1 + r));
      INS1(ts1, pack_si(s01[r], li0 + r));
      INS1(ts1, pack_si(s11[r], li1 + r));
    }
  }
  #undef STAGE

  // merge key-stripes: lanes {lc, lc+16, lc+32, lc+48} hold disjoint stripes of same q-rows
  #pragma unroll
  for (int d = 16; d <= 32; d <<= 1) {
    float os[NC];
    #pragma unroll
    for (int i = 0; i < NC; ++i) os[i] = __shfl_xor(ts0[i], d);
    #pragma unroll
    for (int j = 0; j < NC; ++j) INS1(ts0, os[j]);
    #pragma unroll
    for (int i = 0; i < NC; ++i) os[i] = __shfl_xor(ts1[i], d);
    #pragma unroll
    for (int j = 0; j < NC; ++j) INS1(ts1, os[j]);
  }
#undef INS1
  if (l < 16) {
    int row = rowbase + lc;
    #pragma unroll
    for (int i = 0; i < NC; ++i) {
      unsigned u = __float_as_uint(ts0[i]);
      part_i[(size_t)row * NCAND + seg * NC + i] = seg_start + (int)(u & 0xFFFu);
      part_s[(size_t)row * NCAND + seg * NC + i] = ts0[i];
    }
  } else if (l < 32) {
    int row = rowbase + 16 + lc;
    #pragma unroll
    for (int i = 0; i < NC; ++i) {
      unsigned u = __float_as_uint(ts1[i]);
      part_i[(size_t)row * NCAND + seg * NC + i] = seg_start + (int)(u & 0xFFFu);
      part_s[(size_t)row * NCAND + seg * NC + i] = ts1[i];
    }
  }
}

// ---------------- stage 2: noisy top-10 of 80, exact f64 rescore -> top-5 ----------------
__global__ __launch_bounds__(64) void k_rescore(const float* __restrict__ Q,
                                                const float* __restrict__ mk,
                                                const double* __restrict__ sq64,
                                                const int* __restrict__ part_i,
                                                const float* __restrict__ part_s,
                                                int* __restrict__ idx5) {
  const int row = blockIdx.x;
  const int l = threadIdx.x;
  const float* Qr = Q + (size_t)row * EE;
  float q[8];
  #pragma unroll
  for (int i = 0; i < 8; ++i) q[i] = Qr[l + 64*i];
  float s0 = part_s[(size_t)row * NCAND + l];
  int   i0 = part_i[(size_t)row * NCAND + l];
  float s1 = (l < NCAND - 64) ? part_s[(size_t)row * NCAND + 64 + l] : -3.0e38f;
  int   i1 = (l < NCAND - 64) ? part_i[(size_t)row * NCAND + 64 + l] : 0;

  double bs[5] = {-1e300, -1e300, -1e300, -1e300, -1e300};
  int    bi[5] = {0, 0, 0, 0, 0};
  #pragma unroll
  for (int p = 0; p < NRES; ++p) {
    bool pick0 = (s0 >= s1);
    float m  = pick0 ? s0 : s1;
    int   mi = pick0 ? i0 : i1;
    int   code = (l << 1) | (pick0 ? 0 : 1);
    #pragma unroll
    for (int o = 32; o > 0; o >>= 1) {
      float mo = __shfl_xor(m, o);
      int   io = __shfl_xor(mi, o);
      int   co = __shfl_xor(code, o);
      if (mo > m || (mo == m && co < code)) { m = mo; mi = io; code = co; }
    }
    if ((code >> 1) == l) { if (code & 1) s1 = -3.0e38f; else s0 = -3.0e38f; }
    const float* kr = mk + (size_t)mi * EE;
    double pd = 0.0;
    #pragma unroll
    for (int i = 0; i < 8; ++i) pd += (double)q[i] * (double)kr[l + 64*i];
    #pragma unroll
    for (int o = 32; o > 0; o >>= 1) pd += __shfl_down(pd, o);
    if (l == 0) {
      double s = 2.0 * pd - sq64[mi];
      if (s > bs[4]) {
        bs[4] = s; bi[4] = mi;
        #pragma unroll
        for (int i = 4; i > 0; --i) {
          if (bs[i] > bs[i-1]) {
            double tf = bs[i]; bs[i] = bs[i-1]; bs[i-1] = tf;
            int    tx = bi[i]; bi[i] = bi[i-1]; bi[i-1] = tx;
          }
        }
      }
    }
  }
  if (l == 0) {
    #pragma unroll
    for (int i = 0; i < 5; ++i) idx5[(size_t)row*5 + i] = bi[i];
  }
}

// ---------------- unified 128x64-tile fp16 MFMA GEMM: C = A(rows) @ B^T + bias ----------------
// GATHER: A rows via gidx; AF16: A is f16 (else f32 converted inline); OUTF32: f32 store.
template <int GATHER, int AF16, int OUTF32>
__global__ __launch_bounds__(256) void k_pgemm128(const int* __restrict__ gidx, const void* __restrict__ Asrc,
                                                  const f16* __restrict__ B, const float* __restrict__ bias,
                                                  void* __restrict__ outp) {
  __shared__ f16 As[128][72];
  __shared__ f16 Bs[64][72];
  const int tid = threadIdx.x;
  const int wv = tid >> 6, l = tid & 63, lc = l & 15, lp = l >> 4;
  const int m0 = blockIdx.x * 128, n0 = blockIdx.y * 64;
  const int r0 = tid >> 3;            // 0..31
  const int cb = (tid & 7) * 8;       // f16 col offset within 64
  // hoisted A row pointers (4 rows/thread, fixed across K)
  const f16*   arf[4];
  const float* ar32[4];
  #pragma unroll
  for (int v = 0; v < 4; ++v) {
    int row = m0 + r0 + v * 32;
    int gi = GATHER ? gidx[row] : row;
    if (AF16) arf[v]  = (const f16*)Asrc + (size_t)gi * EE;
    else      ar32[v] = (const float*)Asrc + (size_t)gi * EE;
  }
  const f16* br0 = B + (size_t)(n0 + r0) * EE;
  const f16* br1 = B + (size_t)(n0 + r0 + 32) * EE;
  f32x4 acc[2][4] = {{{0,0,0,0},{0,0,0,0},{0,0,0,0},{0,0,0,0}},
                     {{0,0,0,0},{0,0,0,0},{0,0,0,0},{0,0,0,0}}};
  for (int kb = 0; kb < EE; kb += 64) {
    __syncthreads();
    #pragma unroll
    for (int v = 0; v < 4; ++v) {
      if (AF16) {
        *(f16x8*)&As[r0 + v*32][cb] = *(const f16x8*)(arf[v] + kb + cb);
      } else {
        float4 x0 = *(const float4*)(ar32[v] + kb + cb);
        float4 x1 = *(const float4*)(ar32[v] + kb + cb + 4);
        f16x8 h;
        h[0]=(f16)x0.x; h[1]=(f16)x0.y; h[2]=(f16)x0.z; h[3]=(f16)x0.w;
        h[4]=(f16)x1.x; h[5]=(f16)x1.y; h[6]=(f16)x1.z; h[7]=(f16)x1.w;
        *(f16x8*)&As[r0 + v*32][cb] = h;
      }
    }
    *(f16x8*)&Bs[r0][cb]      = *(const f16x8*)(br0 + kb + cb);
    *(f16x8*)&Bs[r0 + 32][cb] = *(const f16x8*)(br1 + kb + cb);
    __syncthreads();
    #pragma unroll
    for (int ks = 0; ks < 2; ++ks) {
      f16x8 a0 = *(const f16x8*)&As[wv*32 + lc][ks*32 + lp*8];
      f16x8 a1 = *(const f16x8*)&As[wv*32 + 16 + lc][ks*32 + lp*8];
      #pragma unroll
      for (int f = 0; f < 4; ++f) {
        f16x8 b = *(const f16x8*)&Bs[f*16 + lc][ks*32 + lp*8];
        acc[0][f] = __builtin_amdgcn_mfma_f32_16x16x32_f16(a0, b, acc[0][f], 0, 0, 0);
        acc[1][f] = __builtin_amdgcn_mfma_f32_16x16x32_f16(a1, b, acc[1][f], 0, 0, 0);
      }
    }
  }
  #pragma unroll
  for (int g = 0; g < 2; ++g) {
    #pragma unroll
    for (int f = 0; f < 4; ++f) {
      int col = n0 + f*16 + lc;
      float bsv = bias[col];
      #pragma unroll
      for (int rr = 0; rr < 4; ++rr) {
        int row = m0 + wv*32 + g*16 + lp*4 + rr;
        float v = acc[g][f][rr] + bsv;
        if (OUTF32) ((float*)outp)[(size_t)row * EE + col] = v;
        else        ((f16*)outp)[(size_t)row * EE + col] = (f16)v;
      }
    }
  }
}

// ---------------- 5-key MHA (H=8, d=64), f32 compute ----------------
__global__ __launch_bounds__(256) void k_attn(const f16* __restrict__ qp, const f16* __restrict__ kp,
                                              const f16* __restrict__ vp, f16* __restrict__ ao) {
  int row = blockIdx.x * 4 + (threadIdx.x >> 6);
  int l = threadIdx.x & 63;
  int h = l >> 3, sl = l & 7;
  const f16* q = qp + (size_t)row * EE + h * 64 + sl * 8;
  float qv[8];
  #pragma unroll
  for (int i = 0; i < 8; ++i) qv[i] = (float)q[i];
  float sc[5];
  #pragma unroll
  for (int j = 0; j < 5; ++j) {
    const f16* kr = kp + ((size_t)row * 5 + j) * EE + h * 64 + sl * 8;
    float p = 0.f;
    #pragma unroll
    for (int i = 0; i < 8; ++i) p = fmaf(qv[i], (float)kr[i], p);
    p += __shfl_xor(p, 1); p += __shfl_xor(p, 2); p += __shfl_xor(p, 4);
    sc[j] = p * 0.125f;
  }
  float mx = fmaxf(fmaxf(fmaxf(sc[0], sc[1]), fmaxf(sc[2], sc[3])), sc[4]);
  float sum = 0.f;
  #pragma unroll
  for (int j = 0; j < 5; ++j) { sc[j] = __expf(sc[j] - mx); sum += sc[j]; }
  float inv = 1.0f / sum;
  float o[8] = {};
  #pragma unroll
  for (int j = 0; j < 5; ++j) {
    const f16* vr = vp + ((size_t)row * 5 + j) * EE + h * 64 + sl * 8;
    float aw = sc[j] * inv;
    #pragma unroll
    for (int i = 0; i < 8; ++i) o[i] = fmaf(aw, (float)vr[i], o[i]);
  }
  f16* dst = ao + (size_t)row * EE + h * 64 + sl * 8;
  #pragma unroll
  for (int i = 0; i < 8; ++i) dst[i] = (f16)o[i];
}

extern "C" void kernel_launch(void* const* d_in, const int* in_sizes, int n_in,
                              void* d_out, int out_size, void* d_ws, size_t ws_size,
                              hipStream_t stream) {
  const float* Q    = (const float*)d_in[0];
  const float* mk   = (const float*)d_in[1];
  const float* mv   = (const float*)d_in[2];
  const float* Wq   = (const float*)d_in[3];
  const float* bq   = (const float*)d_in[4];
  const float* Wk   = (const float*)d_in[5];
  const float* bk   = (const float*)d_in[6];
  const float* Wv   = (const float*)d_in[7];
  const float* bv   = (const float*)d_in[8];
  const float* Wiq  = (const float*)d_in[9];
  const float* Wik  = (const float*)d_in[10];
  const float* Wiv  = (const float*)d_in[11];
  const float* b_in = (const float*)d_in[12];
  const float* Wo   = (const float*)d_in[13];
  const float* bo   = (const float*)d_in[14];

  char* w = (char*)d_ws;
  size_t off = 0;
  auto alloc = [&](size_t bytes) { size_t o = off; off += (bytes + 255) & ~(size_t)255; return (void*)(w + o); };
  f16*    Kh     = (f16*)   alloc((size_t)NMEM * EE * 2);
  f16*    Qh     = (f16*)   alloc((size_t)BQ * EE * 2);   // dead after stage1 -> ao
  float*  sq32   = (float*) alloc((size_t)NMEM * 4);
  double* sq64   = (double*)alloc((size_t)NMEM * 8);
  f16*    Wc     = (f16*)   alloc((size_t)3 * EE * EE * 2);
  f16*    Wo16   = (f16*)   alloc((size_t)EE * EE * 2);
  float*  bc     = (float*) alloc((size_t)3 * EE * 4);
  int*    part_i = (int*)   alloc((size_t)BQ * NCAND * 4);
  float*  part_s = (float*) alloc((size_t)BQ * NCAND * 4);
  int*    idx5   = (int*)   alloc((size_t)BQ * 5 * 4);
  f16*    qp     = (f16*)   alloc((size_t)BQ * EE * 2);
  f16*    vp     = (f16*)   alloc((size_t)BQ * 5 * EE * 2);
  f16*    ao     = Qh;
  // big tier: separate kp + f16 value table -> gather projections read f16 (half traffic)
  size_t need_big = off + (size_t)NMEM * EE * 2 + (size_t)BQ * 5 * EE * 2 + 4096;
  bool big = (ws_size >= need_big);
  f16* Vh = nullptr;
  f16* kp;
  if (big) {
    Vh = (f16*)alloc((size_t)NMEM * EE * 2);
    kp = (f16*)alloc((size_t)BQ * 5 * EE * 2);
  } else {
    kp = Kh;   // overlay: Kh dead after stage1 in small tier
  }
  (void)in_sizes; (void)n_in; (void)out_size;

  k_prep_keys<<<NMEM / 4, 256, 0, stream>>>(mk, Kh, sq32, sq64);
  k_prep_f16<<<BQ / 4, 256, 0, stream>>>(Q, Qh);
  if (big) k_prep_f16<<<NMEM / 4, 256, 0, stream>>>(mv, Vh);
  k_compose<<<dim3(8, 8, 3), 256, 0, stream>>>(Wq, Wk, Wv, Wiq, Wik, Wiv, Wc);
  k_bias<<<3, 256, 0, stream>>>(Wiq, Wik, Wiv, bq, bk, bv, b_in, bc);
  k_cvtw<<<(EE * EE) / 256, 256, 0, stream>>>(Wo, Wo16);
  k_stage1<<<dim3(BQ / 128, NSEG), 256, 0, stream>>>(Qh, Kh, sq32, part_i, part_s);
  k_rescore<<<BQ, 64, 0, stream>>>(Q, mk, sq64, part_i, part_s, idx5);
  k_pgemm128<0,1,0><<<dim3(BQ / 128, 8), 256, 0, stream>>>(nullptr, Qh, Wc, bc, qp);
  if (big) {
    k_pgemm128<1,1,0><<<dim3(BQ * 5 / 128, 8), 256, 0, stream>>>(idx5, Kh, Wc + (size_t)EE * EE, bc + EE, kp);
    k_pgemm128<1,1,0><<<dim3(BQ * 5 / 128, 8), 256, 0, stream>>>(idx5, Vh, Wc + (size_t)2 * EE * EE, bc + 2 * EE, vp);
  } else {
    k_pgemm128<1,0,0><<<dim3(BQ * 5 / 128, 8), 256, 0, stream>>>(idx5, mk, Wc + (size_t)EE * EE, bc + EE, kp);
    k_pgemm128<1,0,0><<<dim3(BQ * 5 / 128, 8), 256, 0, stream>>>(idx5, mv, Wc + (size_t)2 * EE * EE, bc + 2 * EE, vp);
  }
  k_attn<<<BQ / 4, 256, 0, stream>>>(qp, kp, vp, ao);
  k_pgemm128<0,1,1><<<dim3(BQ / 128, 8), 256, 0, stream>>>(nullptr, ao, Wo16, bo, d_out);
}